// Round 7
// baseline (157.731 us; speedup 1.0000x reference)
//
#include <hip/hip_runtime.h>
#include <hip/hip_bf16.h>

// Shapes (fixed): B=4, SEQ=1024, C=256, H=4, Dk=64, L=4096, N_TOP=SAMPLE_K=36
#define BHn 16
#define Ln 4096
#define NTOP 36
#define SKn 36
#define NCHUNK 64   // l-chunks of 64 for attn partials

using s16x8 = __attribute__((ext_vector_type(8))) short;
using u16x8 = __attribute__((ext_vector_type(8))) unsigned short;
using f32x4 = __attribute__((ext_vector_type(4))) float;

__device__ __forceinline__ unsigned short bf_hi(float f) {
  unsigned u = __float_as_uint(f);
  return (unsigned short)((u + 0x7fffu + ((u >> 16) & 1u)) >> 16);
}

// ---------- W[k][n] f32 -> Wt_hi[n][k], Wt_lo[n][k] bf16 (transposed) -------
__global__ __launch_bounds__(256) void wconv(
    const float* __restrict__ W0, const float* __restrict__ W1, const float* __restrict__ W2,
    unsigned short* __restrict__ th0, unsigned short* __restrict__ tl0,
    unsigned short* __restrict__ th1, unsigned short* __restrict__ tl1,
    unsigned short* __restrict__ th2, unsigned short* __restrict__ tl2) {
  int wsel = blockIdx.y;
  const float* W = (wsel == 0) ? W0 : (wsel == 1) ? W1 : W2;
  unsigned short* TH = (wsel == 0) ? th0 : (wsel == 1) ? th1 : th2;
  unsigned short* TL = (wsel == 0) ? tl0 : (wsel == 1) ? tl1 : tl2;
  int kr = blockIdx.x * 16;
  int n = threadIdx.x;
  u16x8 hv[2], lv[2];
#pragma unroll
  for (int j = 0; j < 16; ++j) {
    float f = W[(size_t)(kr + j) * 256 + n];
    unsigned short h = bf_hi(f);
    float lof = f - __uint_as_float(((unsigned)h) << 16);
    hv[j >> 3][j & 7] = h;
    lv[j >> 3][j & 7] = bf_hi(lof);
  }
  *(u16x8*)&TH[(size_t)n * 256 + kr] = hv[0];
  *(u16x8*)&TH[(size_t)n * 256 + kr + 8] = hv[1];
  *(u16x8*)&TL[(size_t)n * 256 + kr] = lv[0];
  *(u16x8*)&TL[(size_t)n * 256 + kr + 8] = lv[1];
}

// ---------- x permutation-gather -> planar bf16 hi/lo (done ONCE) -----------
__global__ __launch_bounds__(256) void xconv(
    const float* __restrict__ s0, const float* __restrict__ s1,
    const float* __restrict__ s2, const float* __restrict__ s3,
    unsigned short* __restrict__ Axh, unsigned short* __restrict__ Axl) {
  int t = threadIdx.x;
  int row = blockIdx.x * 4 + (t >> 6);
  int c = t & 63;
  int l = row & 4095, b = row >> 12;
  int part = (l >> 2) & 3;
  int seq = ((l >> 4) << 2) | (l & 3);
  const float* sp = (part == 0) ? s0 : (part == 1) ? s1 : (part == 2) ? s2 : s3;
  float4 f = ((const float4*)(sp + (size_t)((b << 10) + seq) * 256))[c];
  float fv[4] = {f.x, f.y, f.z, f.w};
  ushort4 hv, lv;
  unsigned short* hp = (unsigned short*)&hv;
  unsigned short* lp = (unsigned short*)&lv;
#pragma unroll
  for (int j = 0; j < 4; ++j) {
    unsigned short h = bf_hi(fv[j]);
    float lof = fv[j] - __uint_as_float(((unsigned)h) << 16);
    hp[j] = h;
    lp[j] = bf_hi(lof);
  }
  *(ushort4*)&Axh[(size_t)row * 256 + c * 4] = hv;
  *(ushort4*)&Axl[(size_t)row * 256 + c * 4] = lv;
}

// ---------- QKV projection: split-bf16 MFMA, 128x128 tile, BK=32 ------------
// O = x @ W + b ~= Ah*Bh + Ah*Bl + Al*Bh  (f32 accumulate); A pre-converted.
#define LDW 40
__global__ __launch_bounds__(256, 3) void qkv_mfma(
    const unsigned short* __restrict__ Axh, const unsigned short* __restrict__ Axl,
    const unsigned short* __restrict__ th0, const unsigned short* __restrict__ tl0,
    const unsigned short* __restrict__ th1, const unsigned short* __restrict__ tl1,
    const unsigned short* __restrict__ th2, const unsigned short* __restrict__ tl2,
    const float* __restrict__ b0, const float* __restrict__ b1, const float* __restrict__ b2,
    float* __restrict__ o0, float* __restrict__ o1, float* __restrict__ o2) {
  __shared__ __align__(16) unsigned short Ah[128 * LDW];
  __shared__ __align__(16) unsigned short Al[128 * LDW];
  __shared__ __align__(16) unsigned short Bh[128 * LDW];
  __shared__ __align__(16) unsigned short Bl[128 * LDW];
  int t = threadIdx.x;
  int wsel = blockIdx.x >> 1;
  int col0 = (blockIdx.x & 1) * 128;
  int row0 = blockIdx.y * 128;
  const unsigned short* TH = (wsel == 0) ? th0 : (wsel == 1) ? th1 : th2;
  const unsigned short* TL = (wsel == 0) ? tl0 : (wsel == 1) ? tl1 : tl2;
  const float* bias = (wsel == 0) ? b0 : (wsel == 1) ? b1 : b2;
  float* O = (wsel == 0) ? o0 : (wsel == 1) ? o1 : o2;

  int srow = t >> 1, half = t & 1;
  const unsigned short* ah_g = Axh + (size_t)(row0 + srow) * 256 + half * 16;
  const unsigned short* al_g = Axl + (size_t)(row0 + srow) * 256 + half * 16;
  const unsigned short* bh_g = TH + (size_t)(col0 + srow) * 256 + half * 16;
  const unsigned short* bl_g = TL + (size_t)(col0 + srow) * 256 + half * 16;

  int lane = t & 63;
  int wv = t >> 6;
  int wr = wv >> 1, wc = wv & 1;
  int fr = lane & 15, fk = lane >> 4;
  int aoff = (wr * 64 + fr) * LDW + fk * 8;
  int boff = (wc * 64 + fr) * LDW + fk * 8;

  f32x4 acc[4][4] = {};

  for (int k0 = 0; k0 < 256; k0 += 32) {
    int wa = srow * LDW + half * 16;
    u16x8 va0 = *(const u16x8*)(ah_g + k0);
    u16x8 va1 = *(const u16x8*)(ah_g + k0 + 8);
    u16x8 vl0 = *(const u16x8*)(al_g + k0);
    u16x8 vl1 = *(const u16x8*)(al_g + k0 + 8);
    u16x8 vb0 = *(const u16x8*)(bh_g + k0);
    u16x8 vb1 = *(const u16x8*)(bh_g + k0 + 8);
    u16x8 vc0 = *(const u16x8*)(bl_g + k0);
    u16x8 vc1 = *(const u16x8*)(bl_g + k0 + 8);
    *(u16x8*)&Ah[wa] = va0; *(u16x8*)&Ah[wa + 8] = va1;
    *(u16x8*)&Al[wa] = vl0; *(u16x8*)&Al[wa + 8] = vl1;
    *(u16x8*)&Bh[wa] = vb0; *(u16x8*)&Bh[wa + 8] = vb1;
    *(u16x8*)&Bl[wa] = vc0; *(u16x8*)&Bl[wa + 8] = vc1;
    __syncthreads();

    s16x8 fah[4], fal[4];
#pragma unroll
    for (int mi = 0; mi < 4; ++mi) {
      fah[mi] = *(const s16x8*)&Ah[aoff + mi * 16 * LDW];
      fal[mi] = *(const s16x8*)&Al[aoff + mi * 16 * LDW];
    }
#pragma unroll
    for (int ni = 0; ni < 4; ++ni) {
      s16x8 fbh = *(const s16x8*)&Bh[boff + ni * 16 * LDW];
      s16x8 fbl = *(const s16x8*)&Bl[boff + ni * 16 * LDW];
#pragma unroll
      for (int mi = 0; mi < 4; ++mi) {
        acc[mi][ni] = __builtin_amdgcn_mfma_f32_16x16x32_bf16(fah[mi], fbh, acc[mi][ni], 0, 0, 0);
        acc[mi][ni] = __builtin_amdgcn_mfma_f32_16x16x32_bf16(fal[mi], fbh, acc[mi][ni], 0, 0, 0);
        acc[mi][ni] = __builtin_amdgcn_mfma_f32_16x16x32_bf16(fah[mi], fbl, acc[mi][ni], 0, 0, 0);
      }
    }
    __syncthreads();
  }

#pragma unroll
  for (int ni = 0; ni < 4; ++ni) {
    int n = col0 + wc * 64 + ni * 16 + fr;
    float bv = bias[n];
#pragma unroll
    for (int mi = 0; mi < 4; ++mi) {
      int mb = row0 + wr * 64 + mi * 16 + fk * 4;
#pragma unroll
      for (int r = 0; r < 4; ++r)
        O[(size_t)(mb + r) * 256 + n] = acc[mi][ni][r] + bv;
    }
  }
}

// ------------- sampled QK^T and M, XCD-pinned: each XCD owns 2 bh -----------
__global__ __launch_bounds__(256) void qks_m3(
    const float* __restrict__ q, const float* __restrict__ k,
    const int* __restrict__ idxs, float* __restrict__ Mout) {
  __shared__ float qs[64][68];
  __shared__ int il[64 * SKn];
  int g = blockIdx.x;             // 0..1023
  int x = g & 7;                  // XCD (hw round-robin on flat id)
  int i = g >> 3;                 // 0..127
  int bh = (x << 1) | (i >> 6);   // 2 bh per XCD
  int s0 = (i & 63) * 64;
  int t = threadIdx.x;
  size_t base = (size_t)bh << 12;
  for (int i2 = t; i2 < 1024; i2 += 256) {
    int row = i2 >> 4, d4 = i2 & 15;
    *(float4*)&qs[row][d4 * 4] = ((const float4*)(q + (base + s0 + row) * 64))[d4];
  }
  for (int i2 = t; i2 < 64 * SKn; i2 += 256) il[i2] = idxs[s0 * SKn + i2];
  __syncthreads();
  int sl = t >> 2;
  int dq = t & 3;
  float qr[16];
#pragma unroll
  for (int i2 = 0; i2 < 4; ++i2)
    *(float4*)&qr[i2 * 4] = *(const float4*)&qs[sl][i2 * 16 + dq * 4];
  float mx = -INFINITY, sm = 0.f;
  const float4* kb4 = (const float4*)(k + base * 64);
#pragma unroll 4
  for (int j = 0; j < SKn; ++j) {
    int l = il[sl * SKn + j];
    const float4* kr = kb4 + (size_t)l * 16;
    float acc = 0.f;
#pragma unroll
    for (int i2 = 0; i2 < 4; ++i2) {
      float4 kv = kr[i2 * 4 + dq];
      acc += kv.x * qr[i2 * 4] + kv.y * qr[i2 * 4 + 1] + kv.z * qr[i2 * 4 + 2] + kv.w * qr[i2 * 4 + 3];
    }
    acc += __shfl_xor(acc, 1, 64);
    acc += __shfl_xor(acc, 2, 64);
    mx = fmaxf(mx, acc);
    sm += acc;
  }
  if (dq == 0) Mout[base + s0 + sl] = mx - sm * (1.0f / 4096.0f);
}

// ------------- top-36 per (b,h): two-phase radix select ---------------------
__global__ __launch_bounds__(256) void topk_radix(
    const float* __restrict__ M, int* __restrict__ topidx) {
  __shared__ unsigned hist[4096];
  __shared__ unsigned sup[256];
  __shared__ unsigned cand_u[256];
  __shared__ int cand_i[256];
  __shared__ int s_bin1, s_bin2, s_above, s_ocnt, s_ccnt;
  int bh = blockIdx.x;
  int t = threadIdx.x;
  int mbase = bh * 4096;
  unsigned uv[16];
  for (int i = t; i < 4096; i += 256) hist[i] = 0;
  __syncthreads();
#pragma unroll
  for (int r = 0; r < 16; ++r) {
    unsigned b = __float_as_uint(M[mbase + t + 256 * r]);
    unsigned u = b ^ ((unsigned)((int)b >> 31) | 0x80000000u);
    uv[r] = u;
    atomicAdd(&hist[u >> 20], 1u);
  }
  __syncthreads();
  {
    unsigned ssum = 0;
    for (int i = 0; i < 16; ++i) ssum += hist[t * 16 + i];
    sup[t] = ssum;
  }
  __syncthreads();
  if (t == 0) {
    unsigned cum = 0; int sb = 255;
    for (; sb > 0; --sb) { if (cum + sup[sb] >= NTOP) break; cum += sup[sb]; }
    int b = sb * 16 + 15;
    for (; b > sb * 16; --b) { if (cum + hist[b] >= NTOP) break; cum += hist[b]; }
    s_bin1 = b; s_above = (int)cum;
  }
  __syncthreads();
  int bin1 = s_bin1;
  int need1 = NTOP - s_above;
  __syncthreads();
  for (int i = t; i < 4096; i += 256) hist[i] = 0;
  __syncthreads();
#pragma unroll
  for (int r = 0; r < 16; ++r)
    if ((int)(uv[r] >> 20) == bin1) atomicAdd(&hist[(uv[r] >> 8) & 0xFFF], 1u);
  __syncthreads();
  {
    unsigned ssum = 0;
    for (int i = 0; i < 16; ++i) ssum += hist[t * 16 + i];
    sup[t] = ssum;
  }
  __syncthreads();
  if (t == 0) {
    unsigned cum = 0; int sb = 255;
    for (; sb > 0; --sb) { if (cum + sup[sb] >= (unsigned)need1) break; cum += sup[sb]; }
    int b = sb * 16 + 15;
    for (; b > sb * 16; --b) { if (cum + hist[b] >= (unsigned)need1) break; cum += hist[b]; }
    s_bin2 = b; s_above += (int)cum;
    s_ocnt = 0; s_ccnt = 0;
  }
  __syncthreads();
  int bin2 = s_bin2;
  int need = NTOP - s_above;
  int* outp = topidx + bh * NTOP;
#pragma unroll
  for (int r = 0; r < 16; ++r) {
    unsigned u = uv[r];
    int b1 = u >> 20, b2 = (u >> 8) & 0xFFF;
    if (b1 > bin1 || (b1 == bin1 && b2 > bin2)) {
      int p = atomicAdd(&s_ocnt, 1);
      outp[p] = t + 256 * r;
    } else if (b1 == bin1 && b2 == bin2) {
      int p = atomicAdd(&s_ccnt, 1);
      if (p < 256) { cand_u[p] = u; cand_i[p] = t + 256 * r; }
    }
  }
  __syncthreads();
  if (t == 0) {
    int cc = s_ccnt < 256 ? s_ccnt : 256;
    int slot = s_ocnt;
    for (int n = 0; n < need; ++n) {
      unsigned bu = 0; int bi = 0x7fffffff, bp = -1;
      for (int c = 0; c < cc; ++c) {
        if (cand_i[c] < 0) continue;
        if (cand_u[c] > bu || (cand_u[c] == bu && cand_i[c] < bi)) {
          bu = cand_u[c]; bi = cand_i[c]; bp = c;
        }
      }
      outp[slot++] = bi;
      cand_i[bp] = -1;
    }
  }
}

// ------------- v row-sum per (b,h) ------------------------------------------
__global__ __launch_bounds__(256) void vsum_partial(
    const float* __restrict__ v, float* __restrict__ part) {
  __shared__ float4 red[256];
  int bh = blockIdx.x, ch = blockIdx.y;
  int t = threadIdx.x;
  int rg = t >> 4, d4 = t & 15;
  const float4* v4 = (const float4*)(v + ((size_t)bh * 4096 + ch * 256) * 64);
  float4 acc = {0.f, 0.f, 0.f, 0.f};
  for (int r = rg; r < 256; r += 16) {
    float4 x = v4[r * 16 + d4];
    acc.x += x.x; acc.y += x.y; acc.z += x.z; acc.w += x.w;
  }
  red[t] = acc;
  __syncthreads();
  for (int s2 = 8; s2 > 0; s2 >>= 1) {
    if (rg < s2) {
      float4 o = red[(rg + s2) * 16 + d4];
      red[t].x += o.x; red[t].y += o.y; red[t].z += o.z; red[t].w += o.w;
    }
    __syncthreads();
  }
  if (rg == 0) ((float4*)part)[((size_t)bh * 16 + ch) * 16 + d4] = red[d4];
}

__global__ __launch_bounds__(64) void vsum_final(
    const float* __restrict__ part, float* __restrict__ vsum) {
  int bh = blockIdx.x, lane = threadIdx.x;
  float acc = 0.f;
  for (int ch = 0; ch < 16; ++ch) acc += part[((size_t)bh * 16 + ch) * 64 + lane];
  vsum[bh * 64 + lane] = acc;
}

// ------------- attention partials: block per (bh, 64-key chunk) -------------
__global__ __launch_bounds__(256) void attn_partial(
    const float* __restrict__ q, const float* __restrict__ k,
    const float* __restrict__ v, const int* __restrict__ topidx,
    float* __restrict__ part_m, float* __restrict__ part_s,
    float* __restrict__ part_o) {
  __shared__ float4 Ks4[64][17];
  __shared__ float4 qs4[36][17];
  __shared__ float S[36][68];
  int bh = blockIdx.y;
  int c = blockIdx.x;
  int l0 = c * 64;
  int t = threadIdx.x;
  size_t base = (size_t)bh * 4096;

  const float4* kg = (const float4*)(k + (base + l0) * 64);
  for (int i = t; i < 64 * 16; i += 256) {
    int row = i >> 4, d4 = i & 15;
    Ks4[row][d4] = kg[row * 16 + d4];
  }
  for (int i = t; i < 36 * 16; i += 256) {
    int u = i >> 4, d4 = i & 15;
    int m = topidx[bh * NTOP + u];
    qs4[u][d4] = ((const float4*)(q + (base + m) * 64))[d4];
  }
  __syncthreads();

  {
    int l = t & 63, ug = t >> 6;
    float acc[9] = {};
#pragma unroll
    for (int d4 = 0; d4 < 16; ++d4) {
      float4 kv = Ks4[l][d4];
#pragma unroll
      for (int j = 0; j < 9; ++j) {
        float4 qv = qs4[ug * 9 + j][d4];
        acc[j] += kv.x * qv.x + kv.y * qv.y + kv.z * qv.z + kv.w * qv.w;
      }
    }
#pragma unroll
    for (int j = 0; j < 9; ++j) S[ug * 9 + j][l] = acc[j] * 0.125f;
  }
  __syncthreads();

  if (t < NTOP) {
    float mx = -INFINITY;
    for (int l = 0; l < 64; ++l) mx = fmaxf(mx, S[t][l]);
    float sm = 0.f;
    for (int l = 0; l < 64; ++l) { float e = expf(S[t][l] - mx); S[t][l] = e; sm += e; }
    part_m[((size_t)bh * NCHUNK + c) * NTOP + t] = mx;
    part_s[((size_t)bh * NCHUNK + c) * NTOP + t] = sm;
  }
  __syncthreads();

  {
    int d = t & 63, ug = t >> 6;
    float pacc[9] = {};
    const float* vg = v + (base + l0) * 64;
    for (int l = 0; l < 64; ++l) {
      float vv = vg[l * 64 + d];
#pragma unroll
      for (int j = 0; j < 9; ++j) pacc[j] += S[ug * 9 + j][l] * vv;
    }
#pragma unroll
    for (int j = 0; j < 9; ++j)
      part_o[(((size_t)bh * NCHUNK + c) * NTOP + ug * 9 + j) * 64 + d] = pacc[j];
  }
}

// ------------- combine partials -> upd --------------------------------------
__global__ __launch_bounds__(256) void attn_combine(
    const float* __restrict__ part_m, const float* __restrict__ part_s,
    const float* __restrict__ part_o, float* __restrict__ upd) {
  __shared__ float wl[4][64];
  int wave = threadIdx.x >> 6;
  int lane = threadIdx.x & 63;
  int widx = blockIdx.x * 4 + wave;  // bh*36 + u
  int bh = widx / NTOP;
  int u = widx % NTOP;
  float m_c = part_m[((size_t)bh * NCHUNK + lane) * NTOP + u];
  float M = m_c;
#pragma unroll
  for (int off = 32; off > 0; off >>= 1) M = fmaxf(M, __shfl_xor(M, off, 64));
  float w = expf(m_c - M);
  float ds = part_s[((size_t)bh * NCHUNK + lane) * NTOP + u] * w;
#pragma unroll
  for (int off = 32; off > 0; off >>= 1) ds += __shfl_xor(ds, off, 64);
  wl[wave][lane] = w;
  __syncthreads();
  float acc = 0.f;
  for (int c2 = 0; c2 < NCHUNK; ++c2)
    acc += part_o[(((size_t)bh * NCHUNK + c2) * NTOP + u) * 64 + lane] * wl[wave][c2];
  upd[(size_t)widx * 64 + lane] = acc / ds;
}

// ------------- output path --------------------------------------------------
__global__ __launch_bounds__(256) void out_base(
    const float* __restrict__ vsum, const float* __restrict__ Wo,
    const float* __restrict__ bo, float* __restrict__ outbase) {
  __shared__ float xb[64];
  int bh = blockIdx.x, c = threadIdx.x;
  if (c < 64) xb[c] = vsum[bh * 64 + c];
  __syncthreads();
  float acc = bo[c];
#pragma unroll 8
  for (int d = 0; d < 64; ++d) {
    float w4 = Wo[d * 256 + c] + Wo[(64 + d) * 256 + c] +
               Wo[(128 + d) * 256 + c] + Wo[(192 + d) * 256 + c];
    acc += xb[d] * w4;
  }
  outbase[bh * 256 + c] = acc;
}

__global__ __launch_bounds__(256) void out_fill(
    const float* __restrict__ outbase, float4* __restrict__ out4) {
  int g = blockIdx.x * 256 + threadIdx.x;
  int c4 = g & 63;
  int bh = g >> 16;
  out4[g] = ((const float4*)outbase)[bh * 64 + c4];
}

__global__ __launch_bounds__(256) void out_patch(
    const float* __restrict__ upd, const float* __restrict__ vsum,
    const int* __restrict__ topidx, const float* __restrict__ Wo,
    float* __restrict__ out) {
  __shared__ float dv[64];
  int bhu = blockIdx.x;
  int bh = bhu / NTOP;
  int h = bh & 3, b = bh >> 2;
  int t = threadIdx.x;
  if (t < 64) dv[t] = upd[(size_t)bhu * 64 + t] - vsum[bh * 64 + t];
  __syncthreads();
  int m = topidx[bhu];
  int j = m & 3;
  int lp = h * 1024 + (m >> 2);
  float acc = 0.f;
#pragma unroll 8
  for (int d = 0; d < 64; ++d) acc += dv[d] * Wo[(j * 64 + d) * 256 + t];
  atomicAdd(&out[((size_t)(b * 4096 + lp)) * 256 + t], acc);
}

extern "C" void kernel_launch(void* const* d_in, const int* in_sizes, int n_in,
                              void* d_out, int out_size, void* d_ws, size_t ws_size,
                              hipStream_t stream) {
  const float* et  = (const float*)d_in[0];
  const float* mp  = (const float*)d_in[1];
  const float* co  = (const float*)d_in[2];
  const float* vol = (const float*)d_in[3];
  const float* Wq = (const float*)d_in[4];
  const float* bq = (const float*)d_in[5];
  const float* Wk = (const float*)d_in[6];
  const float* bk = (const float*)d_in[7];
  const float* Wv = (const float*)d_in[8];
  const float* bv = (const float*)d_in[9];
  const float* Wo = (const float*)d_in[10];
  const float* bo = (const float*)d_in[11];
  const int* idxs = (const int*)d_in[12];
  float* out = (float*)d_out;

  char* ws = (char*)d_ws;
  const size_t BIG = 16u * 1024u * 1024u;
  float* qb = (float*)(ws);
  float* kb = (float*)(ws + BIG);
  float* vb = (float*)(ws + 2 * BIG);
  char* sm = ws + 3 * BIG;
  float* Mbuf   = (float*)(sm);                                  // 256 KB
  int*   topidx = (int*)(sm + 262144);                           // pad 4 KB
  float* vpart  = (float*)(sm + 262144 + 4096);                  // 64 KB
  float* vsum   = (float*)(sm + 262144 + 4096 + 65536);          // 4 KB
  char* pm = sm + 262144 + 4096 + 65536 + 4096;
  float* part_m = (float*)(pm);                                  // 144 KB
  float* part_s = (float*)(pm + 147456);                         // 144 KB
  float* part_o = (float*)(pm + 2 * 147456);                     // 9.4 MB
  float* updb   = (float*)(pm + 2 * 147456 + 9437184);           // 144 KB
  float* outbase = (float*)(pm + 2 * 147456 + 9437184 + 147456); // 16 KB
  unsigned short* wt = (unsigned short*)(pm + 2 * 147456 + 9437184 + 147456 + 16384);
  unsigned short* wth0 = wt;                 // 6 x 65536 ushort = 768 KB
  unsigned short* wtl0 = wt + 65536;
  unsigned short* wth1 = wt + 2 * 65536;
  unsigned short* wtl1 = wt + 3 * 65536;
  unsigned short* wth2 = wt + 4 * 65536;
  unsigned short* wtl2 = wt + 5 * 65536;
  unsigned short* axh = wt + 6 * 65536;      // 16384x256 ushort = 8 MB
  unsigned short* axl = axh + 16384 * 256;   // 8 MB

  // W -> transposed bf16 hi/lo; x -> permuted planar bf16 hi/lo
  wconv<<<dim3(16, 3), 256, 0, stream>>>(Wq, Wk, Wv, wth0, wtl0, wth1, wtl1, wth2, wtl2);
  xconv<<<4096, 256, 0, stream>>>(et, co, mp, vol, axh, axl);

  // fused QKV projection, split-bf16 MFMA
  qkv_mfma<<<dim3(6, 128), 256, 0, stream>>>(
      axh, axl, wth0, wtl0, wth1, wtl1, wth2, wtl2, bq, bk, bv, qb, kb, vb);

  // sampled scores -> sparsity measure M (XCD-pinned gather)
  qks_m3<<<1024, 256, 0, stream>>>(qb, kb, idxs, Mbuf);

  // top-36 per (b,h), radix select
  topk_radix<<<BHn, 256, 0, stream>>>(Mbuf, topidx);

  // v column sums
  vsum_partial<<<dim3(BHn, 16), 256, 0, stream>>>(vb, vpart);
  vsum_final<<<BHn, 64, 0, stream>>>(vpart, vsum);

  // flash-style attention over selected rows
  attn_partial<<<dim3(NCHUNK, BHn), 256, 0, stream>>>(
      qb, kb, vb, topidx, part_m, part_s, part_o);
  attn_combine<<<144, 256, 0, stream>>>(part_m, part_s, part_o, updb);

  // output: per-(b,h) base rows, broadcast fill, sparse rank-update patches
  out_base<<<BHn, 256, 0, stream>>>(vsum, Wo, bo, outbase);
  out_fill<<<4096, 256, 0, stream>>>(outbase, (float4*)out);
  out_patch<<<BHn * NTOP, 256, 0, stream>>>(updb, vsum, topidx, Wo, out);
}

// Round 8
// 150.065 us; speedup vs baseline: 1.0511x; 1.0511x over previous
//
#include <hip/hip_runtime.h>
#include <hip/hip_bf16.h>

// Shapes (fixed): B=4, SEQ=1024, C=256, H=4, Dk=64, L=4096, N_TOP=SAMPLE_K=36
#define BHn 16
#define Ln 4096
#define NTOP 36
#define SKn 36
#define NCHUNK 64   // l-chunks of 64 for attn partials

using s16x8 = __attribute__((ext_vector_type(8))) short;
using u16x8 = __attribute__((ext_vector_type(8))) unsigned short;
using f32x4 = __attribute__((ext_vector_type(4))) float;

__device__ __forceinline__ unsigned short bf_hi(float f) {
  unsigned u = __float_as_uint(f);
  return (unsigned short)((u + 0x7fffu + ((u >> 16) & 1u)) >> 16);
}

// ---------- W[k][n] f32 -> Wt_hi[n][k], Wt_lo[n][k] bf16 (transposed) -------
__global__ __launch_bounds__(256) void wconv(
    const float* __restrict__ W0, const float* __restrict__ W1, const float* __restrict__ W2,
    unsigned short* __restrict__ th0, unsigned short* __restrict__ tl0,
    unsigned short* __restrict__ th1, unsigned short* __restrict__ tl1,
    unsigned short* __restrict__ th2, unsigned short* __restrict__ tl2) {
  int wsel = blockIdx.y;
  const float* W = (wsel == 0) ? W0 : (wsel == 1) ? W1 : W2;
  unsigned short* TH = (wsel == 0) ? th0 : (wsel == 1) ? th1 : th2;
  unsigned short* TL = (wsel == 0) ? tl0 : (wsel == 1) ? tl1 : tl2;
  int kr = blockIdx.x * 16;
  int n = threadIdx.x;
  u16x8 hv[2], lv[2];
#pragma unroll
  for (int j = 0; j < 16; ++j) {
    float f = W[(size_t)(kr + j) * 256 + n];
    unsigned short h = bf_hi(f);
    float lof = f - __uint_as_float(((unsigned)h) << 16);
    hv[j >> 3][j & 7] = h;
    lv[j >> 3][j & 7] = bf_hi(lof);
  }
  *(u16x8*)&TH[(size_t)n * 256 + kr] = hv[0];
  *(u16x8*)&TH[(size_t)n * 256 + kr + 8] = hv[1];
  *(u16x8*)&TL[(size_t)n * 256 + kr] = lv[0];
  *(u16x8*)&TL[(size_t)n * 256 + kr + 8] = lv[1];
}

// ---------- x permutation-gather -> planar bf16 hi/lo (done ONCE) -----------
__global__ __launch_bounds__(256) void xconv(
    const float* __restrict__ s0, const float* __restrict__ s1,
    const float* __restrict__ s2, const float* __restrict__ s3,
    unsigned short* __restrict__ Axh, unsigned short* __restrict__ Axl) {
  int t = threadIdx.x;
  int row = blockIdx.x * 4 + (t >> 6);
  int c = t & 63;
  int l = row & 4095, b = row >> 12;
  int part = (l >> 2) & 3;
  int seq = ((l >> 4) << 2) | (l & 3);
  const float* sp = (part == 0) ? s0 : (part == 1) ? s1 : (part == 2) ? s2 : s3;
  float4 f = ((const float4*)(sp + (size_t)((b << 10) + seq) * 256))[c];
  float fv[4] = {f.x, f.y, f.z, f.w};
  ushort4 hv, lv;
  unsigned short* hp = (unsigned short*)&hv;
  unsigned short* lp = (unsigned short*)&lv;
#pragma unroll
  for (int j = 0; j < 4; ++j) {
    unsigned short h = bf_hi(fv[j]);
    float lof = fv[j] - __uint_as_float(((unsigned)h) << 16);
    hp[j] = h;
    lp[j] = bf_hi(lof);
  }
  *(ushort4*)&Axh[(size_t)row * 256 + c * 4] = hv;
  *(ushort4*)&Axl[(size_t)row * 256 + c * 4] = lv;
}

// ---------- QKV projection: split-bf16 MFMA, 128x128 tile, BK=32 ------------
// Flat grid 768: variant v = g>>7 (wsel = v>>1, col half = v&1), row = g&127.
// Same-row variants are 128 apart in flat id -> SAME XCD (128 % 8 == 0):
// per-XCD A working set = 2 MB, B = 1.5 MB -> fits 4 MB L2, A fetched once.
// V (wsel==2) uses hi-only bf16 (value path, selection unaffected).
#define LDW 40
__global__ __launch_bounds__(256, 3) void qkv_mfma(
    const unsigned short* __restrict__ Axh, const unsigned short* __restrict__ Axl,
    const unsigned short* __restrict__ th0, const unsigned short* __restrict__ tl0,
    const unsigned short* __restrict__ th1, const unsigned short* __restrict__ tl1,
    const unsigned short* __restrict__ th2, const unsigned short* __restrict__ tl2,
    const float* __restrict__ b0, const float* __restrict__ b1, const float* __restrict__ b2,
    float* __restrict__ o0, float* __restrict__ o1, float* __restrict__ o2) {
  __shared__ __align__(16) unsigned short Ah[128 * LDW];
  __shared__ __align__(16) unsigned short Al[128 * LDW];
  __shared__ __align__(16) unsigned short Bh[128 * LDW];
  __shared__ __align__(16) unsigned short Bl[128 * LDW];
  int t = threadIdx.x;
  int g = blockIdx.x;
  int vnt = g >> 7;           // 0..5
  int wsel = vnt >> 1;
  int col0 = (vnt & 1) * 128;
  int row0 = (g & 127) * 128;
  const unsigned short* TH = (wsel == 0) ? th0 : (wsel == 1) ? th1 : th2;
  const unsigned short* TL = (wsel == 0) ? tl0 : (wsel == 1) ? tl1 : tl2;
  const float* bias = (wsel == 0) ? b0 : (wsel == 1) ? b1 : b2;
  float* O = (wsel == 0) ? o0 : (wsel == 1) ? o1 : o2;
  const bool vlite = (wsel == 2);   // V: hi-only

  int srow = t >> 1, half = t & 1;
  const unsigned short* ah_g = Axh + (size_t)(row0 + srow) * 256 + half * 16;
  const unsigned short* al_g = Axl + (size_t)(row0 + srow) * 256 + half * 16;
  const unsigned short* bh_g = TH + (size_t)(col0 + srow) * 256 + half * 16;
  const unsigned short* bl_g = TL + (size_t)(col0 + srow) * 256 + half * 16;

  int lane = t & 63;
  int wv = t >> 6;
  int wr = wv >> 1, wc = wv & 1;
  int fr = lane & 15, fk = lane >> 4;
  int aoff = (wr * 64 + fr) * LDW + fk * 8;
  int boff = (wc * 64 + fr) * LDW + fk * 8;

  f32x4 acc[4][4] = {};

  for (int k0 = 0; k0 < 256; k0 += 32) {
    int wa = srow * LDW + half * 16;
    u16x8 va0 = *(const u16x8*)(ah_g + k0);
    u16x8 va1 = *(const u16x8*)(ah_g + k0 + 8);
    u16x8 vb0 = *(const u16x8*)(bh_g + k0);
    u16x8 vb1 = *(const u16x8*)(bh_g + k0 + 8);
    *(u16x8*)&Ah[wa] = va0; *(u16x8*)&Ah[wa + 8] = va1;
    *(u16x8*)&Bh[wa] = vb0; *(u16x8*)&Bh[wa + 8] = vb1;
    if (!vlite) {
      u16x8 vl0 = *(const u16x8*)(al_g + k0);
      u16x8 vl1 = *(const u16x8*)(al_g + k0 + 8);
      u16x8 vc0 = *(const u16x8*)(bl_g + k0);
      u16x8 vc1 = *(const u16x8*)(bl_g + k0 + 8);
      *(u16x8*)&Al[wa] = vl0; *(u16x8*)&Al[wa + 8] = vl1;
      *(u16x8*)&Bl[wa] = vc0; *(u16x8*)&Bl[wa + 8] = vc1;
    }
    __syncthreads();

    if (vlite) {
      s16x8 fah[4];
#pragma unroll
      for (int mi = 0; mi < 4; ++mi)
        fah[mi] = *(const s16x8*)&Ah[aoff + mi * 16 * LDW];
#pragma unroll
      for (int ni = 0; ni < 4; ++ni) {
        s16x8 fbh = *(const s16x8*)&Bh[boff + ni * 16 * LDW];
#pragma unroll
        for (int mi = 0; mi < 4; ++mi)
          acc[mi][ni] = __builtin_amdgcn_mfma_f32_16x16x32_bf16(fah[mi], fbh, acc[mi][ni], 0, 0, 0);
      }
    } else {
      s16x8 fah[4], fal[4];
#pragma unroll
      for (int mi = 0; mi < 4; ++mi) {
        fah[mi] = *(const s16x8*)&Ah[aoff + mi * 16 * LDW];
        fal[mi] = *(const s16x8*)&Al[aoff + mi * 16 * LDW];
      }
#pragma unroll
      for (int ni = 0; ni < 4; ++ni) {
        s16x8 fbh = *(const s16x8*)&Bh[boff + ni * 16 * LDW];
        s16x8 fbl = *(const s16x8*)&Bl[boff + ni * 16 * LDW];
#pragma unroll
        for (int mi = 0; mi < 4; ++mi) {
          acc[mi][ni] = __builtin_amdgcn_mfma_f32_16x16x32_bf16(fah[mi], fbh, acc[mi][ni], 0, 0, 0);
          acc[mi][ni] = __builtin_amdgcn_mfma_f32_16x16x32_bf16(fal[mi], fbh, acc[mi][ni], 0, 0, 0);
          acc[mi][ni] = __builtin_amdgcn_mfma_f32_16x16x32_bf16(fah[mi], fbl, acc[mi][ni], 0, 0, 0);
        }
      }
    }
    __syncthreads();
  }

#pragma unroll
  for (int ni = 0; ni < 4; ++ni) {
    int n = col0 + wc * 64 + ni * 16 + fr;
    float bv = bias[n];
#pragma unroll
    for (int mi = 0; mi < 4; ++mi) {
      int mb = row0 + wr * 64 + mi * 16 + fk * 4;
#pragma unroll
      for (int r = 0; r < 4; ++r)
        O[(size_t)(mb + r) * 256 + n] = acc[mi][ni][r] + bv;
    }
  }
}

// ------------- sampled QK^T and M, XCD-pinned: each XCD owns 2 bh -----------
__global__ __launch_bounds__(256) void qks_m3(
    const float* __restrict__ q, const float* __restrict__ k,
    const int* __restrict__ idxs, float* __restrict__ Mout) {
  __shared__ float qs[64][68];
  __shared__ int il[64 * SKn];
  int g = blockIdx.x;             // 0..1023
  int x = g & 7;                  // XCD (hw round-robin on flat id)
  int i = g >> 3;                 // 0..127
  int bh = (x << 1) | (i >> 6);   // 2 bh per XCD
  int s0 = (i & 63) * 64;
  int t = threadIdx.x;
  size_t base = (size_t)bh << 12;
  for (int i2 = t; i2 < 1024; i2 += 256) {
    int row = i2 >> 4, d4 = i2 & 15;
    *(float4*)&qs[row][d4 * 4] = ((const float4*)(q + (base + s0 + row) * 64))[d4];
  }
  for (int i2 = t; i2 < 64 * SKn; i2 += 256) il[i2] = idxs[s0 * SKn + i2];
  __syncthreads();
  int sl = t >> 2;
  int dq = t & 3;
  float qr[16];
#pragma unroll
  for (int i2 = 0; i2 < 4; ++i2)
    *(float4*)&qr[i2 * 4] = *(const float4*)&qs[sl][i2 * 16 + dq * 4];
  float mx = -INFINITY, sm = 0.f;
  const float4* kb4 = (const float4*)(k + base * 64);
#pragma unroll 4
  for (int j = 0; j < SKn; ++j) {
    int l = il[sl * SKn + j];
    const float4* kr = kb4 + (size_t)l * 16;
    float acc = 0.f;
#pragma unroll
    for (int i2 = 0; i2 < 4; ++i2) {
      float4 kv = kr[i2 * 4 + dq];
      acc += kv.x * qr[i2 * 4] + kv.y * qr[i2 * 4 + 1] + kv.z * qr[i2 * 4 + 2] + kv.w * qr[i2 * 4 + 3];
    }
    acc += __shfl_xor(acc, 1, 64);
    acc += __shfl_xor(acc, 2, 64);
    mx = fmaxf(mx, acc);
    sm += acc;
  }
  if (dq == 0) Mout[base + s0 + sl] = mx - sm * (1.0f / 4096.0f);
}

// ------------- top-36 per (b,h): two-phase radix select ---------------------
__global__ __launch_bounds__(256) void topk_radix(
    const float* __restrict__ M, int* __restrict__ topidx) {
  __shared__ unsigned hist[4096];
  __shared__ unsigned sup[256];
  __shared__ unsigned cand_u[256];
  __shared__ int cand_i[256];
  __shared__ int s_bin1, s_bin2, s_above, s_ocnt, s_ccnt;
  int bh = blockIdx.x;
  int t = threadIdx.x;
  int mbase = bh * 4096;
  unsigned uv[16];
  for (int i = t; i < 4096; i += 256) hist[i] = 0;
  __syncthreads();
#pragma unroll
  for (int r = 0; r < 16; ++r) {
    unsigned b = __float_as_uint(M[mbase + t + 256 * r]);
    unsigned u = b ^ ((unsigned)((int)b >> 31) | 0x80000000u);
    uv[r] = u;
    atomicAdd(&hist[u >> 20], 1u);
  }
  __syncthreads();
  {
    unsigned ssum = 0;
    for (int i = 0; i < 16; ++i) ssum += hist[t * 16 + i];
    sup[t] = ssum;
  }
  __syncthreads();
  if (t == 0) {
    unsigned cum = 0; int sb = 255;
    for (; sb > 0; --sb) { if (cum + sup[sb] >= NTOP) break; cum += sup[sb]; }
    int b = sb * 16 + 15;
    for (; b > sb * 16; --b) { if (cum + hist[b] >= NTOP) break; cum += hist[b]; }
    s_bin1 = b; s_above = (int)cum;
  }
  __syncthreads();
  int bin1 = s_bin1;
  int need1 = NTOP - s_above;
  __syncthreads();
  for (int i = t; i < 4096; i += 256) hist[i] = 0;
  __syncthreads();
#pragma unroll
  for (int r = 0; r < 16; ++r)
    if ((int)(uv[r] >> 20) == bin1) atomicAdd(&hist[(uv[r] >> 8) & 0xFFF], 1u);
  __syncthreads();
  {
    unsigned ssum = 0;
    for (int i = 0; i < 16; ++i) ssum += hist[t * 16 + i];
    sup[t] = ssum;
  }
  __syncthreads();
  if (t == 0) {
    unsigned cum = 0; int sb = 255;
    for (; sb > 0; --sb) { if (cum + sup[sb] >= (unsigned)need1) break; cum += sup[sb]; }
    int b = sb * 16 + 15;
    for (; b > sb * 16; --b) { if (cum + hist[b] >= (unsigned)need1) break; cum += hist[b]; }
    s_bin2 = b; s_above += (int)cum;
    s_ocnt = 0; s_ccnt = 0;
  }
  __syncthreads();
  int bin2 = s_bin2;
  int need = NTOP - s_above;
  int* outp = topidx + bh * NTOP;
#pragma unroll
  for (int r = 0; r < 16; ++r) {
    unsigned u = uv[r];
    int b1 = u >> 20, b2 = (u >> 8) & 0xFFF;
    if (b1 > bin1 || (b1 == bin1 && b2 > bin2)) {
      int p = atomicAdd(&s_ocnt, 1);
      outp[p] = t + 256 * r;
    } else if (b1 == bin1 && b2 == bin2) {
      int p = atomicAdd(&s_ccnt, 1);
      if (p < 256) { cand_u[p] = u; cand_i[p] = t + 256 * r; }
    }
  }
  __syncthreads();
  if (t == 0) {
    int cc = s_ccnt < 256 ? s_ccnt : 256;
    int slot = s_ocnt;
    for (int n = 0; n < need; ++n) {
      unsigned bu = 0; int bi = 0x7fffffff, bp = -1;
      for (int c = 0; c < cc; ++c) {
        if (cand_i[c] < 0) continue;
        if (cand_u[c] > bu || (cand_u[c] == bu && cand_i[c] < bi)) {
          bu = cand_u[c]; bi = cand_i[c]; bp = c;
        }
      }
      outp[slot++] = bi;
      cand_i[bp] = -1;
    }
  }
}

// ------------- v row-sum per (b,h) ------------------------------------------
__global__ __launch_bounds__(256) void vsum_partial(
    const float* __restrict__ v, float* __restrict__ part) {
  __shared__ float4 red[256];
  int bh = blockIdx.x, ch = blockIdx.y;
  int t = threadIdx.x;
  int rg = t >> 4, d4 = t & 15;
  const float4* v4 = (const float4*)(v + ((size_t)bh * 4096 + ch * 256) * 64);
  float4 acc = {0.f, 0.f, 0.f, 0.f};
  for (int r = rg; r < 256; r += 16) {
    float4 x = v4[r * 16 + d4];
    acc.x += x.x; acc.y += x.y; acc.z += x.z; acc.w += x.w;
  }
  red[t] = acc;
  __syncthreads();
  for (int s2 = 8; s2 > 0; s2 >>= 1) {
    if (rg < s2) {
      float4 o = red[(rg + s2) * 16 + d4];
      red[t].x += o.x; red[t].y += o.y; red[t].z += o.z; red[t].w += o.w;
    }
    __syncthreads();
  }
  if (rg == 0) ((float4*)part)[((size_t)bh * 16 + ch) * 16 + d4] = red[d4];
}

__global__ __launch_bounds__(64) void vsum_final(
    const float* __restrict__ part, float* __restrict__ vsum) {
  int bh = blockIdx.x, lane = threadIdx.x;
  float acc = 0.f;
  for (int ch = 0; ch < 16; ++ch) acc += part[((size_t)bh * 16 + ch) * 64 + lane];
  vsum[bh * 64 + lane] = acc;
}

// ------------- attention partials, XCD-pinned (2 bh per XCD) ----------------
__global__ __launch_bounds__(256) void attn_partial(
    const float* __restrict__ q, const float* __restrict__ k,
    const float* __restrict__ v, const int* __restrict__ topidx,
    float* __restrict__ part_m, float* __restrict__ part_s,
    float* __restrict__ part_o) {
  __shared__ float4 Ks4[64][17];
  __shared__ float4 qs4[36][17];
  __shared__ float S[36][68];
  int g = blockIdx.x;             // 0..1023
  int x = g & 7;
  int i = g >> 3;
  int bh = (x << 1) | (i >> 6);
  int c = i & 63;
  int l0 = c * 64;
  int t = threadIdx.x;
  size_t base = (size_t)bh * 4096;

  const float4* kg = (const float4*)(k + (base + l0) * 64);
  for (int i2 = t; i2 < 64 * 16; i2 += 256) {
    int row = i2 >> 4, d4 = i2 & 15;
    Ks4[row][d4] = kg[row * 16 + d4];
  }
  for (int i2 = t; i2 < 36 * 16; i2 += 256) {
    int u = i2 >> 4, d4 = i2 & 15;
    int m = topidx[bh * NTOP + u];
    qs4[u][d4] = ((const float4*)(q + (base + m) * 64))[d4];
  }
  __syncthreads();

  {
    int l = t & 63, ug = t >> 6;
    float acc[9] = {};
#pragma unroll
    for (int d4 = 0; d4 < 16; ++d4) {
      float4 kv = Ks4[l][d4];
#pragma unroll
      for (int j = 0; j < 9; ++j) {
        float4 qv = qs4[ug * 9 + j][d4];
        acc[j] += kv.x * qv.x + kv.y * qv.y + kv.z * qv.z + kv.w * qv.w;
      }
    }
#pragma unroll
    for (int j = 0; j < 9; ++j) S[ug * 9 + j][l] = acc[j] * 0.125f;
  }
  __syncthreads();

  if (t < NTOP) {
    float mx = -INFINITY;
    for (int l = 0; l < 64; ++l) mx = fmaxf(mx, S[t][l]);
    float sm = 0.f;
    for (int l = 0; l < 64; ++l) { float e = expf(S[t][l] - mx); S[t][l] = e; sm += e; }
    part_m[((size_t)bh * NCHUNK + c) * NTOP + t] = mx;
    part_s[((size_t)bh * NCHUNK + c) * NTOP + t] = sm;
  }
  __syncthreads();

  {
    int d = t & 63, ug = t >> 6;
    float pacc[9] = {};
    const float* vg = v + (base + l0) * 64;
    for (int l = 0; l < 64; ++l) {
      float vv = vg[l * 64 + d];
#pragma unroll
      for (int j = 0; j < 9; ++j) pacc[j] += S[ug * 9 + j][l] * vv;
    }
#pragma unroll
    for (int j = 0; j < 9; ++j)
      part_o[(((size_t)bh * NCHUNK + c) * NTOP + ug * 9 + j) * 64 + d] = pacc[j];
  }
}

// ------------- combine partials -> upd --------------------------------------
__global__ __launch_bounds__(256) void attn_combine(
    const float* __restrict__ part_m, const float* __restrict__ part_s,
    const float* __restrict__ part_o, float* __restrict__ upd) {
  __shared__ float wl[4][64];
  int wave = threadIdx.x >> 6;
  int lane = threadIdx.x & 63;
  int widx = blockIdx.x * 4 + wave;  // bh*36 + u
  int bh = widx / NTOP;
  int u = widx % NTOP;
  float m_c = part_m[((size_t)bh * NCHUNK + lane) * NTOP + u];
  float M = m_c;
#pragma unroll
  for (int off = 32; off > 0; off >>= 1) M = fmaxf(M, __shfl_xor(M, off, 64));
  float w = expf(m_c - M);
  float ds = part_s[((size_t)bh * NCHUNK + lane) * NTOP + u] * w;
#pragma unroll
  for (int off = 32; off > 0; off >>= 1) ds += __shfl_xor(ds, off, 64);
  wl[wave][lane] = w;
  __syncthreads();
  float acc = 0.f;
  for (int c2 = 0; c2 < NCHUNK; ++c2)
    acc += part_o[(((size_t)bh * NCHUNK + c2) * NTOP + u) * 64 + lane] * wl[wave][c2];
  upd[(size_t)widx * 64 + lane] = acc / ds;
}

// ------------- output path --------------------------------------------------
__global__ __launch_bounds__(256) void out_base(
    const float* __restrict__ vsum, const float* __restrict__ Wo,
    const float* __restrict__ bo, float* __restrict__ outbase) {
  __shared__ float xb[64];
  int bh = blockIdx.x, c = threadIdx.x;
  if (c < 64) xb[c] = vsum[bh * 64 + c];
  __syncthreads();
  float acc = bo[c];
#pragma unroll 8
  for (int d = 0; d < 64; ++d) {
    float w4 = Wo[d * 256 + c] + Wo[(64 + d) * 256 + c] +
               Wo[(128 + d) * 256 + c] + Wo[(192 + d) * 256 + c];
    acc += xb[d] * w4;
  }
  outbase[bh * 256 + c] = acc;
}

__global__ __launch_bounds__(256) void out_fill(
    const float* __restrict__ outbase, float4* __restrict__ out4) {
  int g = blockIdx.x * 256 + threadIdx.x;
  int c4 = g & 63;
  int bh = g >> 16;
  out4[g] = ((const float4*)outbase)[bh * 64 + c4];
}

__global__ __launch_bounds__(256) void out_patch(
    const float* __restrict__ upd, const float* __restrict__ vsum,
    const int* __restrict__ topidx, const float* __restrict__ Wo,
    float* __restrict__ out) {
  __shared__ float dv[64];
  int bhu = blockIdx.x;
  int bh = bhu / NTOP;
  int h = bh & 3, b = bh >> 2;
  int t = threadIdx.x;
  if (t < 64) dv[t] = upd[(size_t)bhu * 64 + t] - vsum[bh * 64 + t];
  __syncthreads();
  int m = topidx[bhu];
  int j = m & 3;
  int lp = h * 1024 + (m >> 2);
  float acc = 0.f;
#pragma unroll 8
  for (int d = 0; d < 64; ++d) acc += dv[d] * Wo[(j * 64 + d) * 256 + t];
  atomicAdd(&out[((size_t)(b * 4096 + lp)) * 256 + t], acc);
}

extern "C" void kernel_launch(void* const* d_in, const int* in_sizes, int n_in,
                              void* d_out, int out_size, void* d_ws, size_t ws_size,
                              hipStream_t stream) {
  const float* et  = (const float*)d_in[0];
  const float* mp  = (const float*)d_in[1];
  const float* co  = (const float*)d_in[2];
  const float* vol = (const float*)d_in[3];
  const float* Wq = (const float*)d_in[4];
  const float* bq = (const float*)d_in[5];
  const float* Wk = (const float*)d_in[6];
  const float* bk = (const float*)d_in[7];
  const float* Wv = (const float*)d_in[8];
  const float* bv = (const float*)d_in[9];
  const float* Wo = (const float*)d_in[10];
  const float* bo = (const float*)d_in[11];
  const int* idxs = (const int*)d_in[12];
  float* out = (float*)d_out;

  char* ws = (char*)d_ws;
  const size_t BIG = 16u * 1024u * 1024u;
  float* qb = (float*)(ws);
  float* kb = (float*)(ws + BIG);
  float* vb = (float*)(ws + 2 * BIG);
  char* sm = ws + 3 * BIG;
  float* Mbuf   = (float*)(sm);                                  // 256 KB
  int*   topidx = (int*)(sm + 262144);                           // pad 4 KB
  float* vpart  = (float*)(sm + 262144 + 4096);                  // 64 KB
  float* vsum   = (float*)(sm + 262144 + 4096 + 65536);          // 4 KB
  char* pm = sm + 262144 + 4096 + 65536 + 4096;
  float* part_m = (float*)(pm);                                  // 144 KB
  float* part_s = (float*)(pm + 147456);                         // 144 KB
  float* part_o = (float*)(pm + 2 * 147456);                     // 9.4 MB
  float* updb   = (float*)(pm + 2 * 147456 + 9437184);           // 144 KB
  float* outbase = (float*)(pm + 2 * 147456 + 9437184 + 147456); // 16 KB
  unsigned short* wt = (unsigned short*)(pm + 2 * 147456 + 9437184 + 147456 + 16384);
  unsigned short* wth0 = wt;                 // 6 x 65536 ushort = 768 KB
  unsigned short* wtl0 = wt + 65536;
  unsigned short* wth1 = wt + 2 * 65536;
  unsigned short* wtl1 = wt + 3 * 65536;
  unsigned short* wth2 = wt + 4 * 65536;
  unsigned short* wtl2 = wt + 5 * 65536;
  unsigned short* axh = wt + 6 * 65536;      // 8 MB
  unsigned short* axl = axh + 16384 * 256;   // 8 MB

  // W -> transposed bf16 hi/lo; x -> permuted planar bf16 hi/lo
  wconv<<<dim3(16, 3), 256, 0, stream>>>(Wq, Wk, Wv, wth0, wtl0, wth1, wtl1, wth2, wtl2);
  xconv<<<4096, 256, 0, stream>>>(et, co, mp, vol, axh, axl);

  // fused QKV projection, split-bf16 MFMA, XCD-swizzled flat grid
  qkv_mfma<<<768, 256, 0, stream>>>(
      axh, axl, wth0, wtl0, wth1, wtl1, wth2, wtl2, bq, bk, bv, qb, kb, vb);

  // sampled scores -> sparsity measure M (XCD-pinned gather)
  qks_m3<<<1024, 256, 0, stream>>>(qb, kb, idxs, Mbuf);

  // top-36 per (b,h), radix select
  topk_radix<<<BHn, 256, 0, stream>>>(Mbuf, topidx);

  // v column sums
  vsum_partial<<<dim3(BHn, 16), 256, 0, stream>>>(vb, vpart);
  vsum_final<<<BHn, 64, 0, stream>>>(vpart, vsum);

  // flash-style attention over selected rows (XCD-pinned)
  attn_partial<<<1024, 256, 0, stream>>>(
      qb, kb, vb, topidx, part_m, part_s, part_o);
  attn_combine<<<144, 256, 0, stream>>>(part_m, part_s, part_o, updb);

  // output: per-(b,h) base rows, broadcast fill, sparse rank-update patches
  out_base<<<BHn, 256, 0, stream>>>(vsum, Wo, bo, outbase);
  out_fill<<<4096, 256, 0, stream>>>(outbase, (float4*)out);
  out_patch<<<BHn * NTOP, 256, 0, stream>>>(updb, vsum, topidx, Wo, out);
}

// Round 9
// 141.065 us; speedup vs baseline: 1.1181x; 1.0638x over previous
//
#include <hip/hip_runtime.h>
#include <hip/hip_bf16.h>

// Shapes (fixed): B=4, SEQ=1024, C=256, H=4, Dk=64, L=4096, N_TOP=SAMPLE_K=36
#define BHn 16
#define Ln 4096
#define NTOP 36
#define SKn 36
#define NCHUNK 64   // l-chunks of 64 for attn partials

using s16x8 = __attribute__((ext_vector_type(8))) short;
using u16x8 = __attribute__((ext_vector_type(8))) unsigned short;
using f32x4 = __attribute__((ext_vector_type(4))) float;

__device__ __forceinline__ unsigned short bf_hi(float f) {
  unsigned u = __float_as_uint(f);
  return (unsigned short)((u + 0x7fffu + ((u >> 16) & 1u)) >> 16);
}

// ---------- merged W-transpose-split + x-gather-split (independent work) ----
// blocks 0..47: W[k][n] f32 -> Wt_hi[n][k], Wt_lo[n][k] bf16
// blocks 48..4143: permuted x -> planar bf16 hi/lo
__global__ __launch_bounds__(256) void wxconv(
    const float* __restrict__ W0, const float* __restrict__ W1, const float* __restrict__ W2,
    unsigned short* __restrict__ th0, unsigned short* __restrict__ tl0,
    unsigned short* __restrict__ th1, unsigned short* __restrict__ tl1,
    unsigned short* __restrict__ th2, unsigned short* __restrict__ tl2,
    const float* __restrict__ s0, const float* __restrict__ s1,
    const float* __restrict__ s2, const float* __restrict__ s3,
    unsigned short* __restrict__ Axh, unsigned short* __restrict__ Axl) {
  int bx = blockIdx.x;
  int t = threadIdx.x;
  if (bx < 48) {
    int wsel = bx >> 4;
    const float* W = (wsel == 0) ? W0 : (wsel == 1) ? W1 : W2;
    unsigned short* TH = (wsel == 0) ? th0 : (wsel == 1) ? th1 : th2;
    unsigned short* TL = (wsel == 0) ? tl0 : (wsel == 1) ? tl1 : tl2;
    int kr = (bx & 15) * 16;
    int n = t;
    u16x8 hv[2], lv[2];
#pragma unroll
    for (int j = 0; j < 16; ++j) {
      float f = W[(size_t)(kr + j) * 256 + n];
      unsigned short h = bf_hi(f);
      float lof = f - __uint_as_float(((unsigned)h) << 16);
      hv[j >> 3][j & 7] = h;
      lv[j >> 3][j & 7] = bf_hi(lof);
    }
    *(u16x8*)&TH[(size_t)n * 256 + kr] = hv[0];
    *(u16x8*)&TH[(size_t)n * 256 + kr + 8] = hv[1];
    *(u16x8*)&TL[(size_t)n * 256 + kr] = lv[0];
    *(u16x8*)&TL[(size_t)n * 256 + kr + 8] = lv[1];
  } else {
    int row = (bx - 48) * 4 + (t >> 6);
    int c = t & 63;
    int l = row & 4095, b = row >> 12;
    int part = (l >> 2) & 3;
    int seq = ((l >> 4) << 2) | (l & 3);
    const float* sp = (part == 0) ? s0 : (part == 1) ? s1 : (part == 2) ? s2 : s3;
    float4 f = ((const float4*)(sp + (size_t)((b << 10) + seq) * 256))[c];
    float fv[4] = {f.x, f.y, f.z, f.w};
    ushort4 hv, lv;
    unsigned short* hp = (unsigned short*)&hv;
    unsigned short* lp = (unsigned short*)&lv;
#pragma unroll
    for (int j = 0; j < 4; ++j) {
      unsigned short h = bf_hi(fv[j]);
      float lof = fv[j] - __uint_as_float(((unsigned)h) << 16);
      hp[j] = h;
      lp[j] = bf_hi(lof);
    }
    *(ushort4*)&Axh[(size_t)row * 256 + c * 4] = hv;
    *(ushort4*)&Axl[(size_t)row * 256 + c * 4] = lv;
  }
}

// ---------- QKV projection: split-bf16 MFMA, 128x128 tile, BK=32 ------------
// Flat grid 768: variant v = g>>7, row = g&127; same-row variants 128 apart
// -> same XCD -> A fetched once per XCD (L2-resident). V (wsel==2) hi-only.
#define LDW 40
__global__ __launch_bounds__(256, 3) void qkv_mfma(
    const unsigned short* __restrict__ Axh, const unsigned short* __restrict__ Axl,
    const unsigned short* __restrict__ th0, const unsigned short* __restrict__ tl0,
    const unsigned short* __restrict__ th1, const unsigned short* __restrict__ tl1,
    const unsigned short* __restrict__ th2, const unsigned short* __restrict__ tl2,
    const float* __restrict__ b0, const float* __restrict__ b1, const float* __restrict__ b2,
    float* __restrict__ o0, float* __restrict__ o1, float* __restrict__ o2) {
  __shared__ __align__(16) unsigned short Ah[128 * LDW];
  __shared__ __align__(16) unsigned short Al[128 * LDW];
  __shared__ __align__(16) unsigned short Bh[128 * LDW];
  __shared__ __align__(16) unsigned short Bl[128 * LDW];
  int t = threadIdx.x;
  int g = blockIdx.x;
  int vnt = g >> 7;           // 0..5
  int wsel = vnt >> 1;
  int col0 = (vnt & 1) * 128;
  int row0 = (g & 127) * 128;
  const unsigned short* TH = (wsel == 0) ? th0 : (wsel == 1) ? th1 : th2;
  const unsigned short* TL = (wsel == 0) ? tl0 : (wsel == 1) ? tl1 : tl2;
  const float* bias = (wsel == 0) ? b0 : (wsel == 1) ? b1 : b2;
  float* O = (wsel == 0) ? o0 : (wsel == 1) ? o1 : o2;
  const bool vlite = (wsel == 2);   // V: hi-only

  int srow = t >> 1, half = t & 1;
  const unsigned short* ah_g = Axh + (size_t)(row0 + srow) * 256 + half * 16;
  const unsigned short* al_g = Axl + (size_t)(row0 + srow) * 256 + half * 16;
  const unsigned short* bh_g = TH + (size_t)(col0 + srow) * 256 + half * 16;
  const unsigned short* bl_g = TL + (size_t)(col0 + srow) * 256 + half * 16;

  int lane = t & 63;
  int wv = t >> 6;
  int wr = wv >> 1, wc = wv & 1;
  int fr = lane & 15, fk = lane >> 4;
  int aoff = (wr * 64 + fr) * LDW + fk * 8;
  int boff = (wc * 64 + fr) * LDW + fk * 8;

  f32x4 acc[4][4] = {};

  for (int k0 = 0; k0 < 256; k0 += 32) {
    int wa = srow * LDW + half * 16;
    u16x8 va0 = *(const u16x8*)(ah_g + k0);
    u16x8 va1 = *(const u16x8*)(ah_g + k0 + 8);
    u16x8 vb0 = *(const u16x8*)(bh_g + k0);
    u16x8 vb1 = *(const u16x8*)(bh_g + k0 + 8);
    *(u16x8*)&Ah[wa] = va0; *(u16x8*)&Ah[wa + 8] = va1;
    *(u16x8*)&Bh[wa] = vb0; *(u16x8*)&Bh[wa + 8] = vb1;
    if (!vlite) {
      u16x8 vl0 = *(const u16x8*)(al_g + k0);
      u16x8 vl1 = *(const u16x8*)(al_g + k0 + 8);
      u16x8 vc0 = *(const u16x8*)(bl_g + k0);
      u16x8 vc1 = *(const u16x8*)(bl_g + k0 + 8);
      *(u16x8*)&Al[wa] = vl0; *(u16x8*)&Al[wa + 8] = vl1;
      *(u16x8*)&Bl[wa] = vc0; *(u16x8*)&Bl[wa + 8] = vc1;
    }
    __syncthreads();

    if (vlite) {
      s16x8 fah[4];
#pragma unroll
      for (int mi = 0; mi < 4; ++mi)
        fah[mi] = *(const s16x8*)&Ah[aoff + mi * 16 * LDW];
#pragma unroll
      for (int ni = 0; ni < 4; ++ni) {
        s16x8 fbh = *(const s16x8*)&Bh[boff + ni * 16 * LDW];
#pragma unroll
        for (int mi = 0; mi < 4; ++mi)
          acc[mi][ni] = __builtin_amdgcn_mfma_f32_16x16x32_bf16(fah[mi], fbh, acc[mi][ni], 0, 0, 0);
      }
    } else {
      s16x8 fah[4], fal[4];
#pragma unroll
      for (int mi = 0; mi < 4; ++mi) {
        fah[mi] = *(const s16x8*)&Ah[aoff + mi * 16 * LDW];
        fal[mi] = *(const s16x8*)&Al[aoff + mi * 16 * LDW];
      }
#pragma unroll
      for (int ni = 0; ni < 4; ++ni) {
        s16x8 fbh = *(const s16x8*)&Bh[boff + ni * 16 * LDW];
        s16x8 fbl = *(const s16x8*)&Bl[boff + ni * 16 * LDW];
#pragma unroll
        for (int mi = 0; mi < 4; ++mi) {
          acc[mi][ni] = __builtin_amdgcn_mfma_f32_16x16x32_bf16(fah[mi], fbh, acc[mi][ni], 0, 0, 0);
          acc[mi][ni] = __builtin_amdgcn_mfma_f32_16x16x32_bf16(fal[mi], fbh, acc[mi][ni], 0, 0, 0);
          acc[mi][ni] = __builtin_amdgcn_mfma_f32_16x16x32_bf16(fah[mi], fbl, acc[mi][ni], 0, 0, 0);
        }
      }
    }
    __syncthreads();
  }

#pragma unroll
  for (int ni = 0; ni < 4; ++ni) {
    int n = col0 + wc * 64 + ni * 16 + fr;
    float bv = bias[n];
#pragma unroll
    for (int mi = 0; mi < 4; ++mi) {
      int mb = row0 + wr * 64 + mi * 16 + fk * 4;
#pragma unroll
      for (int r = 0; r < 4; ++r)
        O[(size_t)(mb + r) * 256 + n] = acc[mi][ni][r] + bv;
    }
  }
}

// ------------- sampled QK^T and M, XCD-pinned: each XCD owns 2 bh -----------
__global__ __launch_bounds__(256) void qks_m3(
    const float* __restrict__ q, const float* __restrict__ k,
    const int* __restrict__ idxs, float* __restrict__ Mout) {
  __shared__ float qs[64][68];
  __shared__ int il[64 * SKn];
  int g = blockIdx.x;             // 0..1023
  int x = g & 7;                  // XCD (hw round-robin on flat id)
  int i = g >> 3;                 // 0..127
  int bh = (x << 1) | (i >> 6);   // 2 bh per XCD
  int s0 = (i & 63) * 64;
  int t = threadIdx.x;
  size_t base = (size_t)bh << 12;
  for (int i2 = t; i2 < 1024; i2 += 256) {
    int row = i2 >> 4, d4 = i2 & 15;
    *(float4*)&qs[row][d4 * 4] = ((const float4*)(q + (base + s0 + row) * 64))[d4];
  }
  for (int i2 = t; i2 < 64 * SKn; i2 += 256) il[i2] = idxs[s0 * SKn + i2];
  __syncthreads();
  int sl = t >> 2;
  int dq = t & 3;
  float qr[16];
#pragma unroll
  for (int i2 = 0; i2 < 4; ++i2)
    *(float4*)&qr[i2 * 4] = *(const float4*)&qs[sl][i2 * 16 + dq * 4];
  float mx = -INFINITY, sm = 0.f;
  const float4* kb4 = (const float4*)(k + base * 64);
#pragma unroll 4
  for (int j = 0; j < SKn; ++j) {
    int l = il[sl * SKn + j];
    const float4* kr = kb4 + (size_t)l * 16;
    float acc = 0.f;
#pragma unroll
    for (int i2 = 0; i2 < 4; ++i2) {
      float4 kv = kr[i2 * 4 + dq];
      acc += kv.x * qr[i2 * 4] + kv.y * qr[i2 * 4 + 1] + kv.z * qr[i2 * 4 + 2] + kv.w * qr[i2 * 4 + 3];
    }
    acc += __shfl_xor(acc, 1, 64);
    acc += __shfl_xor(acc, 2, 64);
    mx = fmaxf(mx, acc);
    sm += acc;
  }
  if (dq == 0) Mout[base + s0 + sl] = mx - sm * (1.0f / 4096.0f);
}

// ------------- top-36 per (b,h): two-phase radix select ---------------------
__global__ __launch_bounds__(256) void topk_radix(
    const float* __restrict__ M, int* __restrict__ topidx) {
  __shared__ unsigned hist[4096];
  __shared__ unsigned sup[256];
  __shared__ unsigned cand_u[256];
  __shared__ int cand_i[256];
  __shared__ int s_bin1, s_bin2, s_above, s_ocnt, s_ccnt;
  int bh = blockIdx.x;
  int t = threadIdx.x;
  int mbase = bh * 4096;
  unsigned uv[16];
  for (int i = t; i < 4096; i += 256) hist[i] = 0;
  __syncthreads();
#pragma unroll
  for (int r = 0; r < 16; ++r) {
    unsigned b = __float_as_uint(M[mbase + t + 256 * r]);
    unsigned u = b ^ ((unsigned)((int)b >> 31) | 0x80000000u);
    uv[r] = u;
    atomicAdd(&hist[u >> 20], 1u);
  }
  __syncthreads();
  {
    unsigned ssum = 0;
    for (int i = 0; i < 16; ++i) ssum += hist[t * 16 + i];
    sup[t] = ssum;
  }
  __syncthreads();
  if (t == 0) {
    unsigned cum = 0; int sb = 255;
    for (; sb > 0; --sb) { if (cum + sup[sb] >= NTOP) break; cum += sup[sb]; }
    int b = sb * 16 + 15;
    for (; b > sb * 16; --b) { if (cum + hist[b] >= NTOP) break; cum += hist[b]; }
    s_bin1 = b; s_above = (int)cum;
  }
  __syncthreads();
  int bin1 = s_bin1;
  int need1 = NTOP - s_above;
  __syncthreads();
  for (int i = t; i < 4096; i += 256) hist[i] = 0;
  __syncthreads();
#pragma unroll
  for (int r = 0; r < 16; ++r)
    if ((int)(uv[r] >> 20) == bin1) atomicAdd(&hist[(uv[r] >> 8) & 0xFFF], 1u);
  __syncthreads();
  {
    unsigned ssum = 0;
    for (int i = 0; i < 16; ++i) ssum += hist[t * 16 + i];
    sup[t] = ssum;
  }
  __syncthreads();
  if (t == 0) {
    unsigned cum = 0; int sb = 255;
    for (; sb > 0; --sb) { if (cum + sup[sb] >= (unsigned)need1) break; cum += sup[sb]; }
    int b = sb * 16 + 15;
    for (; b > sb * 16; --b) { if (cum + hist[b] >= (unsigned)need1) break; cum += hist[b]; }
    s_bin2 = b; s_above += (int)cum;
    s_ocnt = 0; s_ccnt = 0;
  }
  __syncthreads();
  int bin2 = s_bin2;
  int need = NTOP - s_above;
  int* outp = topidx + bh * NTOP;
#pragma unroll
  for (int r = 0; r < 16; ++r) {
    unsigned u = uv[r];
    int b1 = u >> 20, b2 = (u >> 8) & 0xFFF;
    if (b1 > bin1 || (b1 == bin1 && b2 > bin2)) {
      int p = atomicAdd(&s_ocnt, 1);
      outp[p] = t + 256 * r;
    } else if (b1 == bin1 && b2 == bin2) {
      int p = atomicAdd(&s_ccnt, 1);
      if (p < 256) { cand_u[p] = u; cand_i[p] = t + 256 * r; }
    }
  }
  __syncthreads();
  if (t == 0) {
    int cc = s_ccnt < 256 ? s_ccnt : 256;
    int slot = s_ocnt;
    for (int n = 0; n < need; ++n) {
      unsigned bu = 0; int bi = 0x7fffffff, bp = -1;
      for (int c = 0; c < cc; ++c) {
        if (cand_i[c] < 0) continue;
        if (cand_u[c] > bu || (cand_u[c] == bu && cand_i[c] < bi)) {
          bu = cand_u[c]; bi = cand_i[c]; bp = c;
        }
      }
      outp[slot++] = bi;
      cand_i[bp] = -1;
    }
  }
}

// ------------- attention partials + fused V chunk-sum, XCD-pinned -----------
__global__ __launch_bounds__(256) void attn_partial(
    const float* __restrict__ q, const float* __restrict__ k,
    const float* __restrict__ v, const int* __restrict__ topidx,
    float* __restrict__ part_m, float* __restrict__ part_s,
    float* __restrict__ part_o, float* __restrict__ vpart2) {
  __shared__ float4 Ks4[64][17];
  __shared__ float4 qs4[36][17];
  __shared__ float S[36][68];
  int g = blockIdx.x;             // 0..1023
  int x = g & 7;
  int i = g >> 3;
  int bh = (x << 1) | (i >> 6);
  int c = i & 63;
  int l0 = c * 64;
  int t = threadIdx.x;
  size_t base = (size_t)bh * 4096;

  const float4* kg = (const float4*)(k + (base + l0) * 64);
  for (int i2 = t; i2 < 64 * 16; i2 += 256) {
    int row = i2 >> 4, d4 = i2 & 15;
    Ks4[row][d4] = kg[row * 16 + d4];
  }
  for (int i2 = t; i2 < 36 * 16; i2 += 256) {
    int u = i2 >> 4, d4 = i2 & 15;
    int m = topidx[bh * NTOP + u];
    qs4[u][d4] = ((const float4*)(q + (base + m) * 64))[d4];
  }
  __syncthreads();

  {
    int l = t & 63, ug = t >> 6;
    float acc[9] = {};
#pragma unroll
    for (int d4 = 0; d4 < 16; ++d4) {
      float4 kv = Ks4[l][d4];
#pragma unroll
      for (int j = 0; j < 9; ++j) {
        float4 qv = qs4[ug * 9 + j][d4];
        acc[j] += kv.x * qv.x + kv.y * qv.y + kv.z * qv.z + kv.w * qv.w;
      }
    }
#pragma unroll
    for (int j = 0; j < 9; ++j) S[ug * 9 + j][l] = acc[j] * 0.125f;
  }
  __syncthreads();

  if (t < NTOP) {
    float mx = -INFINITY;
    for (int l = 0; l < 64; ++l) mx = fmaxf(mx, S[t][l]);
    float sm = 0.f;
    for (int l = 0; l < 64; ++l) { float e = expf(S[t][l] - mx); S[t][l] = e; sm += e; }
    part_m[((size_t)bh * NCHUNK + c) * NTOP + t] = mx;
    part_s[((size_t)bh * NCHUNK + c) * NTOP + t] = sm;
  }
  __syncthreads();

  {
    int d = t & 63, ug = t >> 6;
    float pacc[9] = {};
    float vs = 0.f;
    const float* vg = v + (base + l0) * 64;
    for (int l = 0; l < 64; ++l) {
      float vv = vg[l * 64 + d];
      vs += vv;
#pragma unroll
      for (int j = 0; j < 9; ++j) pacc[j] += S[ug * 9 + j][l] * vv;
    }
#pragma unroll
    for (int j = 0; j < 9; ++j)
      part_o[(((size_t)bh * NCHUNK + c) * NTOP + ug * 9 + j) * 64 + d] = pacc[j];
    if (ug == 0) vpart2[((size_t)bh * NCHUNK + c) * 64 + d] = vs;
  }
}

// ------------- combine partials -> upd --------------------------------------
__global__ __launch_bounds__(256) void attn_combine(
    const float* __restrict__ part_m, const float* __restrict__ part_s,
    const float* __restrict__ part_o, float* __restrict__ upd) {
  __shared__ float wl[4][64];
  int wave = threadIdx.x >> 6;
  int lane = threadIdx.x & 63;
  int widx = blockIdx.x * 4 + wave;  // bh*36 + u
  int bh = widx / NTOP;
  int u = widx % NTOP;
  float m_c = part_m[((size_t)bh * NCHUNK + lane) * NTOP + u];
  float M = m_c;
#pragma unroll
  for (int off = 32; off > 0; off >>= 1) M = fmaxf(M, __shfl_xor(M, off, 64));
  float w = expf(m_c - M);
  float ds = part_s[((size_t)bh * NCHUNK + lane) * NTOP + u] * w;
#pragma unroll
  for (int off = 32; off > 0; off >>= 1) ds += __shfl_xor(ds, off, 64);
  wl[wave][lane] = w;
  __syncthreads();
  float acc = 0.f;
  for (int c2 = 0; c2 < NCHUNK; ++c2)
    acc += part_o[(((size_t)bh * NCHUNK + c2) * NTOP + u) * 64 + lane] * wl[wave][c2];
  upd[(size_t)widx * 64 + lane] = acc / ds;
}

// ------------- vsum reduce + per-(b,h) base output row (fused) --------------
__global__ __launch_bounds__(256) void vsum_out(
    const float* __restrict__ vpart2, const float* __restrict__ Wo,
    const float* __restrict__ bo, float* __restrict__ vsum,
    float* __restrict__ outbase) {
  __shared__ float red[4][64];
  __shared__ float vs[64];
  int bh = blockIdx.x;
  int t = threadIdx.x;
  int d = t & 63, qq = t >> 6;
  float acc = 0.f;
  for (int c = qq; c < NCHUNK; c += 4)
    acc += vpart2[((size_t)bh * NCHUNK + c) * 64 + d];
  red[qq][d] = acc;
  __syncthreads();
  if (qq == 0) {
    float s = red[0][d] + red[1][d] + red[2][d] + red[3][d];
    vs[d] = s;
    vsum[bh * 64 + d] = s;
  }
  __syncthreads();
  float ob = bo[t];
#pragma unroll 8
  for (int dd = 0; dd < 64; ++dd) {
    float w4 = Wo[dd * 256 + t] + Wo[(64 + dd) * 256 + t] +
               Wo[(128 + dd) * 256 + t] + Wo[(192 + dd) * 256 + t];
    ob += vs[dd] * w4;
  }
  outbase[bh * 256 + t] = ob;
}

// ------------- output fill + sparse patches ---------------------------------
__global__ __launch_bounds__(256) void out_fill(
    const float* __restrict__ outbase, float4* __restrict__ out4) {
  int g = blockIdx.x * 256 + threadIdx.x;
  int c4 = g & 63;
  int bh = g >> 16;
  out4[g] = ((const float4*)outbase)[bh * 64 + c4];
}

__global__ __launch_bounds__(256) void out_patch(
    const float* __restrict__ upd, const float* __restrict__ vsum,
    const int* __restrict__ topidx, const float* __restrict__ Wo,
    float* __restrict__ out) {
  __shared__ float dv[64];
  int bhu = blockIdx.x;
  int bh = bhu / NTOP;
  int h = bh & 3, b = bh >> 2;
  int t = threadIdx.x;
  if (t < 64) dv[t] = upd[(size_t)bhu * 64 + t] - vsum[bh * 64 + t];
  __syncthreads();
  int m = topidx[bhu];
  int j = m & 3;
  int lp = h * 1024 + (m >> 2);
  float acc = 0.f;
#pragma unroll 8
  for (int d = 0; d < 64; ++d) acc += dv[d] * Wo[(j * 64 + d) * 256 + t];
  atomicAdd(&out[((size_t)(b * 4096 + lp)) * 256 + t], acc);
}

extern "C" void kernel_launch(void* const* d_in, const int* in_sizes, int n_in,
                              void* d_out, int out_size, void* d_ws, size_t ws_size,
                              hipStream_t stream) {
  const float* et  = (const float*)d_in[0];
  const float* mp  = (const float*)d_in[1];
  const float* co  = (const float*)d_in[2];
  const float* vol = (const float*)d_in[3];
  const float* Wq = (const float*)d_in[4];
  const float* bq = (const float*)d_in[5];
  const float* Wk = (const float*)d_in[6];
  const float* bk = (const float*)d_in[7];
  const float* Wv = (const float*)d_in[8];
  const float* bv = (const float*)d_in[9];
  const float* Wo = (const float*)d_in[10];
  const float* bo = (const float*)d_in[11];
  const int* idxs = (const int*)d_in[12];
  float* out = (float*)d_out;

  char* ws = (char*)d_ws;
  const size_t BIG = 16u * 1024u * 1024u;
  float* qb = (float*)(ws);
  float* kb = (float*)(ws + BIG);
  float* vb = (float*)(ws + 2 * BIG);
  char* sm = ws + 3 * BIG;
  float* Mbuf   = (float*)(sm);                                  // 256 KB
  int*   topidx = (int*)(sm + 262144);                           // pad 4 KB
  float* vsum   = (float*)(sm + 262144 + 4096);                  // 4 KB (pad 8K)
  char* pm = sm + 262144 + 4096 + 8192;
  float* part_m = (float*)(pm);                                  // 144 KB
  float* part_s = (float*)(pm + 147456);                         // 144 KB
  float* part_o = (float*)(pm + 2 * 147456);                     // 9.4 MB
  float* updb   = (float*)(pm + 2 * 147456 + 9437184);           // 144 KB
  float* outbase = (float*)(pm + 2 * 147456 + 9437184 + 147456); // 16 KB
  unsigned short* wt = (unsigned short*)(pm + 2 * 147456 + 9437184 + 147456 + 16384);
  unsigned short* wth0 = wt;                 // 6 x 65536 ushort = 768 KB
  unsigned short* wtl0 = wt + 65536;
  unsigned short* wth1 = wt + 2 * 65536;
  unsigned short* wtl1 = wt + 3 * 65536;
  unsigned short* wth2 = wt + 4 * 65536;
  unsigned short* wtl2 = wt + 5 * 65536;
  unsigned short* axh = wt + 6 * 65536;      // 8 MB
  unsigned short* axl = axh + 16384 * 256;   // 8 MB
  float* vpart2 = (float*)(axl + 16384 * 256); // 16*64*64*4 = 256 KB

  // W -> transposed bf16 hi/lo; x -> permuted planar bf16 hi/lo (one kernel)
  wxconv<<<4144, 256, 0, stream>>>(Wq, Wk, Wv, wth0, wtl0, wth1, wtl1, wth2, wtl2,
                                   et, co, mp, vol, axh, axl);

  // fused QKV projection, split-bf16 MFMA, XCD-swizzled flat grid
  qkv_mfma<<<768, 256, 0, stream>>>(
      axh, axl, wth0, wtl0, wth1, wtl1, wth2, wtl2, bq, bk, bv, qb, kb, vb);

  // sampled scores -> sparsity measure M (XCD-pinned gather)
  qks_m3<<<1024, 256, 0, stream>>>(qb, kb, idxs, Mbuf);

  // top-36 per (b,h), radix select
  topk_radix<<<BHn, 256, 0, stream>>>(Mbuf, topidx);

  // flash-style attention over selected rows (XCD-pinned) + V chunk-sums
  attn_partial<<<1024, 256, 0, stream>>>(
      qb, kb, vb, topidx, part_m, part_s, part_o, vpart2);
  attn_combine<<<144, 256, 0, stream>>>(part_m, part_s, part_o, updb);

  // vsum reduce + per-(b,h) base rows (fused)
  vsum_out<<<BHn, 256, 0, stream>>>(vpart2, Wo, bo, vsum, outbase);

  // output: broadcast fill, sparse rank-update patches
  out_fill<<<4096, 256, 0, stream>>>(outbase, (float4*)out);
  out_patch<<<BHn * NTOP, 256, 0, stream>>>(updb, vsum, topidx, Wo, out);
}

// Round 10
// 127.404 us; speedup vs baseline: 1.2380x; 1.1072x over previous
//
#include <hip/hip_runtime.h>
#include <hip/hip_bf16.h>

// Shapes (fixed): B=4, SEQ=1024, C=256, H=4, Dk=64, L=4096, N_TOP=SAMPLE_K=36
#define BHn 16
#define Ln 4096
#define NTOP 36
#define SKn 36
#define NCHUNK 64   // l-chunks of 64 for attn partials

using s16x8 = __attribute__((ext_vector_type(8))) short;
using u16x8 = __attribute__((ext_vector_type(8))) unsigned short;
using f32x4 = __attribute__((ext_vector_type(4))) float;

__device__ __forceinline__ unsigned short bf_hi(float f) {
  unsigned u = __float_as_uint(f);
  return (unsigned short)((u + 0x7fffu + ((u >> 16) & 1u)) >> 16);
}

// ---------- merged W-transpose-split + x-gather-split (independent work) ----
__global__ __launch_bounds__(256) void wxconv(
    const float* __restrict__ W0, const float* __restrict__ W1, const float* __restrict__ W2,
    unsigned short* __restrict__ th0, unsigned short* __restrict__ tl0,
    unsigned short* __restrict__ th1, unsigned short* __restrict__ tl1,
    unsigned short* __restrict__ th2, unsigned short* __restrict__ tl2,
    const float* __restrict__ s0, const float* __restrict__ s1,
    const float* __restrict__ s2, const float* __restrict__ s3,
    unsigned short* __restrict__ Axh, unsigned short* __restrict__ Axl) {
  int bx = blockIdx.x;
  int t = threadIdx.x;
  if (bx < 48) {
    int wsel = bx >> 4;
    const float* W = (wsel == 0) ? W0 : (wsel == 1) ? W1 : W2;
    unsigned short* TH = (wsel == 0) ? th0 : (wsel == 1) ? th1 : th2;
    unsigned short* TL = (wsel == 0) ? tl0 : (wsel == 1) ? tl1 : tl2;
    int kr = (bx & 15) * 16;
    int n = t;
    u16x8 hv[2], lv[2];
#pragma unroll
    for (int j = 0; j < 16; ++j) {
      float f = W[(size_t)(kr + j) * 256 + n];
      unsigned short h = bf_hi(f);
      float lof = f - __uint_as_float(((unsigned)h) << 16);
      hv[j >> 3][j & 7] = h;
      lv[j >> 3][j & 7] = bf_hi(lof);
    }
    *(u16x8*)&TH[(size_t)n * 256 + kr] = hv[0];
    *(u16x8*)&TH[(size_t)n * 256 + kr + 8] = hv[1];
    *(u16x8*)&TL[(size_t)n * 256 + kr] = lv[0];
    *(u16x8*)&TL[(size_t)n * 256 + kr + 8] = lv[1];
  } else {
    int row = (bx - 48) * 4 + (t >> 6);
    int c = t & 63;
    int l = row & 4095, b = row >> 12;
    int part = (l >> 2) & 3;
    int seq = ((l >> 4) << 2) | (l & 3);
    const float* sp = (part == 0) ? s0 : (part == 1) ? s1 : (part == 2) ? s2 : s3;
    float4 f = ((const float4*)(sp + (size_t)((b << 10) + seq) * 256))[c];
    float fv[4] = {f.x, f.y, f.z, f.w};
    ushort4 hv, lv;
    unsigned short* hp = (unsigned short*)&hv;
    unsigned short* lp = (unsigned short*)&lv;
#pragma unroll
    for (int j = 0; j < 4; ++j) {
      unsigned short h = bf_hi(fv[j]);
      float lof = fv[j] - __uint_as_float(((unsigned)h) << 16);
      hp[j] = h;
      lp[j] = bf_hi(lof);
    }
    *(ushort4*)&Axh[(size_t)row * 256 + c * 4] = hv;
    *(ushort4*)&Axl[(size_t)row * 256 + c * 4] = lv;
  }
}

// ---------- QKV projection: split-bf16 MFMA, 128x128 tile, BK=32 ------------
#define LDW 40
__global__ __launch_bounds__(256, 3) void qkv_mfma(
    const unsigned short* __restrict__ Axh, const unsigned short* __restrict__ Axl,
    const unsigned short* __restrict__ th0, const unsigned short* __restrict__ tl0,
    const unsigned short* __restrict__ th1, const unsigned short* __restrict__ tl1,
    const unsigned short* __restrict__ th2, const unsigned short* __restrict__ tl2,
    const float* __restrict__ b0, const float* __restrict__ b1, const float* __restrict__ b2,
    float* __restrict__ o0, float* __restrict__ o1, float* __restrict__ o2) {
  __shared__ __align__(16) unsigned short Ah[128 * LDW];
  __shared__ __align__(16) unsigned short Al[128 * LDW];
  __shared__ __align__(16) unsigned short Bh[128 * LDW];
  __shared__ __align__(16) unsigned short Bl[128 * LDW];
  int t = threadIdx.x;
  int g = blockIdx.x;
  int vnt = g >> 7;           // 0..5
  int wsel = vnt >> 1;
  int col0 = (vnt & 1) * 128;
  int row0 = (g & 127) * 128;
  const unsigned short* TH = (wsel == 0) ? th0 : (wsel == 1) ? th1 : th2;
  const unsigned short* TL = (wsel == 0) ? tl0 : (wsel == 1) ? tl1 : tl2;
  const float* bias = (wsel == 0) ? b0 : (wsel == 1) ? b1 : b2;
  float* O = (wsel == 0) ? o0 : (wsel == 1) ? o1 : o2;
  const bool vlite = (wsel == 2);   // V: hi-only

  int srow = t >> 1, half = t & 1;
  const unsigned short* ah_g = Axh + (size_t)(row0 + srow) * 256 + half * 16;
  const unsigned short* al_g = Axl + (size_t)(row0 + srow) * 256 + half * 16;
  const unsigned short* bh_g = TH + (size_t)(col0 + srow) * 256 + half * 16;
  const unsigned short* bl_g = TL + (size_t)(col0 + srow) * 256 + half * 16;

  int lane = t & 63;
  int wv = t >> 6;
  int wr = wv >> 1, wc = wv & 1;
  int fr = lane & 15, fk = lane >> 4;
  int aoff = (wr * 64 + fr) * LDW + fk * 8;
  int boff = (wc * 64 + fr) * LDW + fk * 8;

  f32x4 acc[4][4] = {};

  for (int k0 = 0; k0 < 256; k0 += 32) {
    int wa = srow * LDW + half * 16;
    u16x8 va0 = *(const u16x8*)(ah_g + k0);
    u16x8 va1 = *(const u16x8*)(ah_g + k0 + 8);
    u16x8 vb0 = *(const u16x8*)(bh_g + k0);
    u16x8 vb1 = *(const u16x8*)(bh_g + k0 + 8);
    *(u16x8*)&Ah[wa] = va0; *(u16x8*)&Ah[wa + 8] = va1;
    *(u16x8*)&Bh[wa] = vb0; *(u16x8*)&Bh[wa + 8] = vb1;
    if (!vlite) {
      u16x8 vl0 = *(const u16x8*)(al_g + k0);
      u16x8 vl1 = *(const u16x8*)(al_g + k0 + 8);
      u16x8 vc0 = *(const u16x8*)(bl_g + k0);
      u16x8 vc1 = *(const u16x8*)(bl_g + k0 + 8);
      *(u16x8*)&Al[wa] = vl0; *(u16x8*)&Al[wa + 8] = vl1;
      *(u16x8*)&Bl[wa] = vc0; *(u16x8*)&Bl[wa + 8] = vc1;
    }
    __syncthreads();

    if (vlite) {
      s16x8 fah[4];
#pragma unroll
      for (int mi = 0; mi < 4; ++mi)
        fah[mi] = *(const s16x8*)&Ah[aoff + mi * 16 * LDW];
#pragma unroll
      for (int ni = 0; ni < 4; ++ni) {
        s16x8 fbh = *(const s16x8*)&Bh[boff + ni * 16 * LDW];
#pragma unroll
        for (int mi = 0; mi < 4; ++mi)
          acc[mi][ni] = __builtin_amdgcn_mfma_f32_16x16x32_bf16(fah[mi], fbh, acc[mi][ni], 0, 0, 0);
      }
    } else {
      s16x8 fah[4], fal[4];
#pragma unroll
      for (int mi = 0; mi < 4; ++mi) {
        fah[mi] = *(const s16x8*)&Ah[aoff + mi * 16 * LDW];
        fal[mi] = *(const s16x8*)&Al[aoff + mi * 16 * LDW];
      }
#pragma unroll
      for (int ni = 0; ni < 4; ++ni) {
        s16x8 fbh = *(const s16x8*)&Bh[boff + ni * 16 * LDW];
        s16x8 fbl = *(const s16x8*)&Bl[boff + ni * 16 * LDW];
#pragma unroll
        for (int mi = 0; mi < 4; ++mi) {
          acc[mi][ni] = __builtin_amdgcn_mfma_f32_16x16x32_bf16(fah[mi], fbh, acc[mi][ni], 0, 0, 0);
          acc[mi][ni] = __builtin_amdgcn_mfma_f32_16x16x32_bf16(fal[mi], fbh, acc[mi][ni], 0, 0, 0);
          acc[mi][ni] = __builtin_amdgcn_mfma_f32_16x16x32_bf16(fah[mi], fbl, acc[mi][ni], 0, 0, 0);
        }
      }
    }
    __syncthreads();
  }

#pragma unroll
  for (int ni = 0; ni < 4; ++ni) {
    int n = col0 + wc * 64 + ni * 16 + fr;
    float bv = bias[n];
#pragma unroll
    for (int mi = 0; mi < 4; ++mi) {
      int mb = row0 + wr * 64 + mi * 16 + fk * 4;
#pragma unroll
      for (int r = 0; r < 4; ++r)
        O[(size_t)(mb + r) * 256 + n] = acc[mi][ni][r] + bv;
    }
  }
}

// ------------- sampled QK^T and M, XCD-pinned: each XCD owns 2 bh -----------
__global__ __launch_bounds__(256) void qks_m3(
    const float* __restrict__ q, const float* __restrict__ k,
    const int* __restrict__ idxs, float* __restrict__ Mout) {
  __shared__ float qs[64][68];
  __shared__ int il[64 * SKn];
  int g = blockIdx.x;             // 0..1023
  int x = g & 7;                  // XCD (hw round-robin on flat id)
  int i = g >> 3;                 // 0..127
  int bh = (x << 1) | (i >> 6);   // 2 bh per XCD
  int s0 = (i & 63) * 64;
  int t = threadIdx.x;
  size_t base = (size_t)bh << 12;
  for (int i2 = t; i2 < 1024; i2 += 256) {
    int row = i2 >> 4, d4 = i2 & 15;
    *(float4*)&qs[row][d4 * 4] = ((const float4*)(q + (base + s0 + row) * 64))[d4];
  }
  for (int i2 = t; i2 < 64 * SKn; i2 += 256) il[i2] = idxs[s0 * SKn + i2];
  __syncthreads();
  int sl = t >> 2;
  int dq = t & 3;
  float qr[16];
#pragma unroll
  for (int i2 = 0; i2 < 4; ++i2)
    *(float4*)&qr[i2 * 4] = *(const float4*)&qs[sl][i2 * 16 + dq * 4];
  float mx = -INFINITY, sm = 0.f;
  const float4* kb4 = (const float4*)(k + base * 64);
#pragma unroll 4
  for (int j = 0; j < SKn; ++j) {
    int l = il[sl * SKn + j];
    const float4* kr = kb4 + (size_t)l * 16;
    float acc = 0.f;
#pragma unroll
    for (int i2 = 0; i2 < 4; ++i2) {
      float4 kv = kr[i2 * 4 + dq];
      acc += kv.x * qr[i2 * 4] + kv.y * qr[i2 * 4 + 1] + kv.z * qr[i2 * 4 + 2] + kv.w * qr[i2 * 4 + 3];
    }
    acc += __shfl_xor(acc, 1, 64);
    acc += __shfl_xor(acc, 2, 64);
    mx = fmaxf(mx, acc);
    sm += acc;
  }
  if (dq == 0) Mout[base + s0 + sl] = mx - sm * (1.0f / 4096.0f);
}

// ------------- top-36 per (b,h): two-phase radix select ---------------------
__global__ __launch_bounds__(256) void topk_radix(
    const float* __restrict__ M, int* __restrict__ topidx) {
  __shared__ unsigned hist[4096];
  __shared__ unsigned sup[256];
  __shared__ unsigned cand_u[256];
  __shared__ int cand_i[256];
  __shared__ int s_bin1, s_bin2, s_above, s_ocnt, s_ccnt;
  int bh = blockIdx.x;
  int t = threadIdx.x;
  int mbase = bh * 4096;
  unsigned uv[16];
  for (int i = t; i < 4096; i += 256) hist[i] = 0;
  __syncthreads();
#pragma unroll
  for (int r = 0; r < 16; ++r) {
    unsigned b = __float_as_uint(M[mbase + t + 256 * r]);
    unsigned u = b ^ ((unsigned)((int)b >> 31) | 0x80000000u);
    uv[r] = u;
    atomicAdd(&hist[u >> 20], 1u);
  }
  __syncthreads();
  {
    unsigned ssum = 0;
    for (int i = 0; i < 16; ++i) ssum += hist[t * 16 + i];
    sup[t] = ssum;
  }
  __syncthreads();
  if (t == 0) {
    unsigned cum = 0; int sb = 255;
    for (; sb > 0; --sb) { if (cum + sup[sb] >= NTOP) break; cum += sup[sb]; }
    int b = sb * 16 + 15;
    for (; b > sb * 16; --b) { if (cum + hist[b] >= NTOP) break; cum += hist[b]; }
    s_bin1 = b; s_above = (int)cum;
  }
  __syncthreads();
  int bin1 = s_bin1;
  int need1 = NTOP - s_above;
  __syncthreads();
  for (int i = t; i < 4096; i += 256) hist[i] = 0;
  __syncthreads();
#pragma unroll
  for (int r = 0; r < 16; ++r)
    if ((int)(uv[r] >> 20) == bin1) atomicAdd(&hist[(uv[r] >> 8) & 0xFFF], 1u);
  __syncthreads();
  {
    unsigned ssum = 0;
    for (int i = 0; i < 16; ++i) ssum += hist[t * 16 + i];
    sup[t] = ssum;
  }
  __syncthreads();
  if (t == 0) {
    unsigned cum = 0; int sb = 255;
    for (; sb > 0; --sb) { if (cum + sup[sb] >= (unsigned)need1) break; cum += sup[sb]; }
    int b = sb * 16 + 15;
    for (; b > sb * 16; --b) { if (cum + hist[b] >= (unsigned)need1) break; cum += hist[b]; }
    s_bin2 = b; s_above += (int)cum;
    s_ocnt = 0; s_ccnt = 0;
  }
  __syncthreads();
  int bin2 = s_bin2;
  int need = NTOP - s_above;
  int* outp = topidx + bh * NTOP;
#pragma unroll
  for (int r = 0; r < 16; ++r) {
    unsigned u = uv[r];
    int b1 = u >> 20, b2 = (u >> 8) & 0xFFF;
    if (b1 > bin1 || (b1 == bin1 && b2 > bin2)) {
      int p = atomicAdd(&s_ocnt, 1);
      outp[p] = t + 256 * r;
    } else if (b1 == bin1 && b2 == bin2) {
      int p = atomicAdd(&s_ccnt, 1);
      if (p < 256) { cand_u[p] = u; cand_i[p] = t + 256 * r; }
    }
  }
  __syncthreads();
  if (t == 0) {
    int cc = s_ccnt < 256 ? s_ccnt : 256;
    int slot = s_ocnt;
    for (int n = 0; n < need; ++n) {
      unsigned bu = 0; int bi = 0x7fffffff, bp = -1;
      for (int c = 0; c < cc; ++c) {
        if (cand_i[c] < 0) continue;
        if (cand_u[c] > bu || (cand_u[c] == bu && cand_i[c] < bi)) {
          bu = cand_u[c]; bi = cand_i[c]; bp = c;
        }
      }
      outp[slot++] = bi;
      cand_i[bp] = -1;
    }
  }
}

// ------------- attention partials + fused V chunk-sum, XCD-pinned -----------
// part_o stored bf16 (value path only). Softmax wave-parallel: 4 lanes/row.
__global__ __launch_bounds__(256) void attn_partial(
    const float* __restrict__ q, const float* __restrict__ k,
    const float* __restrict__ v, const int* __restrict__ topidx,
    float* __restrict__ part_m, float* __restrict__ part_s,
    unsigned short* __restrict__ part_ob, float* __restrict__ vpart2) {
  __shared__ float4 Ks4[64][17];
  __shared__ float4 qs4[36][17];
  __shared__ float S[36][68];
  int g = blockIdx.x;             // 0..1023
  int x = g & 7;
  int i = g >> 3;
  int bh = (x << 1) | (i >> 6);
  int c = i & 63;
  int l0 = c * 64;
  int t = threadIdx.x;
  size_t base = (size_t)bh * 4096;

  const float4* kg = (const float4*)(k + (base + l0) * 64);
  for (int i2 = t; i2 < 64 * 16; i2 += 256) {
    int row = i2 >> 4, d4 = i2 & 15;
    Ks4[row][d4] = kg[row * 16 + d4];
  }
  for (int i2 = t; i2 < 36 * 16; i2 += 256) {
    int u = i2 >> 4, d4 = i2 & 15;
    int m = topidx[bh * NTOP + u];
    qs4[u][d4] = ((const float4*)(q + (base + m) * 64))[d4];
  }
  __syncthreads();

  {
    int l = t & 63, ug = t >> 6;
    float acc[9] = {};
#pragma unroll
    for (int d4 = 0; d4 < 16; ++d4) {
      float4 kv = Ks4[l][d4];
#pragma unroll
      for (int j = 0; j < 9; ++j) {
        float4 qv = qs4[ug * 9 + j][d4];
        acc[j] += kv.x * qv.x + kv.y * qv.y + kv.z * qv.z + kv.w * qv.w;
      }
    }
#pragma unroll
    for (int j = 0; j < 9; ++j) S[ug * 9 + j][l] = acc[j] * 0.125f;
  }
  __syncthreads();

  // wave-parallel partial softmax: row u handled by 4 lanes (t = u*4+p)
  if (t < 144) {
    int u = t >> 2, p = t & 3;
    int lb = p * 16;
    float mx = -INFINITY;
#pragma unroll
    for (int l2 = 0; l2 < 16; ++l2) mx = fmaxf(mx, S[u][lb + l2]);
    mx = fmaxf(mx, __shfl_xor(mx, 1, 64));
    mx = fmaxf(mx, __shfl_xor(mx, 2, 64));
    float sm = 0.f;
#pragma unroll
    for (int l2 = 0; l2 < 16; ++l2) {
      float e = expf(S[u][lb + l2] - mx);
      S[u][lb + l2] = e;
      sm += e;
    }
    sm += __shfl_xor(sm, 1, 64);
    sm += __shfl_xor(sm, 2, 64);
    if (p == 0) {
      part_m[((size_t)bh * NCHUNK + c) * NTOP + u] = mx;
      part_s[((size_t)bh * NCHUNK + c) * NTOP + u] = sm;
    }
  }
  __syncthreads();

  {
    int d = t & 63, ug = t >> 6;
    float pacc[9] = {};
    float vs = 0.f;
    const float* vg = v + (base + l0) * 64;
    for (int l = 0; l < 64; ++l) {
      float vv = vg[l * 64 + d];
      vs += vv;
#pragma unroll
      for (int j = 0; j < 9; ++j) pacc[j] += S[ug * 9 + j][l] * vv;
    }
#pragma unroll
    for (int j = 0; j < 9; ++j)
      part_ob[(((size_t)bh * NCHUNK + c) * NTOP + ug * 9 + j) * 64 + d] = bf_hi(pacc[j]);
    if (ug == 0) vpart2[((size_t)bh * NCHUNK + c) * 64 + d] = vs;
  }
}

// ------------- vsum reduce + per-(b,h) base output row (fused) --------------
__global__ __launch_bounds__(256) void vsum_out(
    const float* __restrict__ vpart2, const float* __restrict__ Wo,
    const float* __restrict__ bo, float* __restrict__ vsum,
    float* __restrict__ outbase) {
  __shared__ float red[4][64];
  __shared__ float vs[64];
  int bh = blockIdx.x;
  int t = threadIdx.x;
  int d = t & 63, qq = t >> 6;
  float acc = 0.f;
  for (int c = qq; c < NCHUNK; c += 4)
    acc += vpart2[((size_t)bh * NCHUNK + c) * 64 + d];
  red[qq][d] = acc;
  __syncthreads();
  if (qq == 0) {
    float s = red[0][d] + red[1][d] + red[2][d] + red[3][d];
    vs[d] = s;
    vsum[bh * 64 + d] = s;
  }
  __syncthreads();
  float ob = bo[t];
#pragma unroll 8
  for (int dd = 0; dd < 64; ++dd) {
    float w4 = Wo[dd * 256 + t] + Wo[(64 + dd) * 256 + t] +
               Wo[(128 + dd) * 256 + t] + Wo[(192 + dd) * 256 + t];
    ob += vs[dd] * w4;
  }
  outbase[bh * 256 + t] = ob;
}

// ------------- output fill ---------------------------------------------------
__global__ __launch_bounds__(256) void out_fill(
    const float* __restrict__ outbase, float4* __restrict__ out4) {
  int g = blockIdx.x * 256 + threadIdx.x;
  int c4 = g & 63;
  int bh = g >> 16;
  out4[g] = ((const float4*)outbase)[bh * 64 + c4];
}

// ------------- merged combine + sparse patch (one block per (bh,u)) ---------
__global__ __launch_bounds__(256) void combine_patch(
    const float* __restrict__ part_m, const float* __restrict__ part_s,
    const unsigned short* __restrict__ part_ob, const float* __restrict__ vsum,
    const int* __restrict__ topidx, const float* __restrict__ Wo,
    float* __restrict__ out) {
  __shared__ float wl[64];
  __shared__ float red[4][64];
  __shared__ float dv[64];
  __shared__ float ds_s;
  int widx = blockIdx.x;          // 0..575 = bh*36 + u
  int bh = widx / NTOP;
  int u = widx % NTOP;
  int t = threadIdx.x;
  int d = t & 63, qq = t >> 6;
  if (t < 64) {
    float m_c = part_m[((size_t)bh * NCHUNK + t) * NTOP + u];
    float M = m_c;
#pragma unroll
    for (int off = 32; off > 0; off >>= 1) M = fmaxf(M, __shfl_xor(M, off, 64));
    float w = expf(m_c - M);
    float ds = part_s[((size_t)bh * NCHUNK + t) * NTOP + u] * w;
#pragma unroll
    for (int off = 32; off > 0; off >>= 1) ds += __shfl_xor(ds, off, 64);
    wl[t] = w;
    if (t == 0) ds_s = ds;
  }
  __syncthreads();
  float acc = 0.f;
#pragma unroll
  for (int j = 0; j < 16; ++j) {
    int c = qq + j * 4;
    float po = __uint_as_float(
        ((unsigned)part_ob[(((size_t)bh * NCHUNK + c) * NTOP + u) * 64 + d]) << 16);
    acc += po * wl[c];
  }
  red[qq][d] = acc;
  __syncthreads();
  if (qq == 0)
    dv[d] = (red[0][d] + red[1][d] + red[2][d] + red[3][d]) / ds_s - vsum[bh * 64 + d];
  __syncthreads();
  int m = topidx[widx];
  int h = bh & 3, b = bh >> 2;
  int j2 = m & 3;
  int lp = h * 1024 + (m >> 2);
  float acc2 = 0.f;
#pragma unroll 8
  for (int dd = 0; dd < 64; ++dd) acc2 += dv[dd] * Wo[(j2 * 64 + dd) * 256 + t];
  atomicAdd(&out[((size_t)(b * 4096 + lp)) * 256 + t], acc2);
}

extern "C" void kernel_launch(void* const* d_in, const int* in_sizes, int n_in,
                              void* d_out, int out_size, void* d_ws, size_t ws_size,
                              hipStream_t stream) {
  const float* et  = (const float*)d_in[0];
  const float* mp  = (const float*)d_in[1];
  const float* co  = (const float*)d_in[2];
  const float* vol = (const float*)d_in[3];
  const float* Wq = (const float*)d_in[4];
  const float* bq = (const float*)d_in[5];
  const float* Wk = (const float*)d_in[6];
  const float* bk = (const float*)d_in[7];
  const float* Wv = (const float*)d_in[8];
  const float* bv = (const float*)d_in[9];
  const float* Wo = (const float*)d_in[10];
  const float* bo = (const float*)d_in[11];
  const int* idxs = (const int*)d_in[12];
  float* out = (float*)d_out;

  char* ws = (char*)d_ws;
  const size_t BIG = 16u * 1024u * 1024u;
  float* qb = (float*)(ws);
  float* kb = (float*)(ws + BIG);
  float* vb = (float*)(ws + 2 * BIG);
  char* sm = ws + 3 * BIG;
  float* Mbuf   = (float*)(sm);                                  // 256 KB
  int*   topidx = (int*)(sm + 262144);                           // pad 4 KB
  float* vsum   = (float*)(sm + 262144 + 4096);                  // 4 KB (pad 8K)
  char* pm = sm + 262144 + 4096 + 8192;
  float* part_m = (float*)(pm);                                  // 144 KB
  float* part_s = (float*)(pm + 147456);                         // 144 KB
  unsigned short* part_ob = (unsigned short*)(pm + 2 * 147456);  // 4.7 MB
  float* outbase = (float*)(pm + 2 * 147456 + 4718592);          // 16 KB
  unsigned short* wt = (unsigned short*)(pm + 2 * 147456 + 4718592 + 16384);
  unsigned short* wth0 = wt;                 // 6 x 65536 ushort = 768 KB
  unsigned short* wtl0 = wt + 65536;
  unsigned short* wth1 = wt + 2 * 65536;
  unsigned short* wtl1 = wt + 3 * 65536;
  unsigned short* wth2 = wt + 4 * 65536;
  unsigned short* wtl2 = wt + 5 * 65536;
  unsigned short* axh = wt + 6 * 65536;      // 8 MB
  unsigned short* axl = axh + 16384 * 256;   // 8 MB
  float* vpart2 = (float*)(axl + 16384 * 256); // 256 KB

  // W -> transposed bf16 hi/lo; x -> permuted planar bf16 hi/lo (one kernel)
  wxconv<<<4144, 256, 0, stream>>>(Wq, Wk, Wv, wth0, wtl0, wth1, wtl1, wth2, wtl2,
                                   et, co, mp, vol, axh, axl);

  // fused QKV projection, split-bf16 MFMA, XCD-swizzled flat grid
  qkv_mfma<<<768, 256, 0, stream>>>(
      axh, axl, wth0, wtl0, wth1, wtl1, wth2, wtl2, bq, bk, bv, qb, kb, vb);

  // sampled scores -> sparsity measure M (XCD-pinned gather)
  qks_m3<<<1024, 256, 0, stream>>>(qb, kb, idxs, Mbuf);

  // top-36 per (b,h), radix select
  topk_radix<<<BHn, 256, 0, stream>>>(Mbuf, topidx);

  // flash-style attention over selected rows (XCD-pinned) + V chunk-sums
  attn_partial<<<1024, 256, 0, stream>>>(
      qb, kb, vb, topidx, part_m, part_s, part_ob, vpart2);

  // vsum reduce + per-(b,h) base rows (fused)
  vsum_out<<<BHn, 256, 0, stream>>>(vpart2, Wo, bo, vsum, outbase);

  // base fill must precede the atomic patches
  out_fill<<<4096, 256, 0, stream>>>(outbase, (float4*)out);

  // merge partials -> upd -> rank-update patch (fused)
  combine_patch<<<BHn * NTOP, 256, 0, stream>>>(
      part_m, part_s, part_ob, vsum, topidx, Wo, out);
}